// Round 17
// baseline (595.060 us; speedup 1.0000x reference)
//
#include <hip/hip_runtime.h>
#include <hip/hip_bf16.h>

typedef __bf16 bf16_t;
typedef __attribute__((ext_vector_type(4))) float f32x4;
typedef __attribute__((ext_vector_type(8))) int i32x8;

#define FD 1024
#define HD 256
#define GG 4096

// pack 4 f32 -> 4 OCP e4m3 bytes (v_cvt_pk_fp8_f32, gfx950 = OCP)
__device__ inline unsigned int pack4_fp8(float a, float b, float c, float d) {
    int v = __builtin_amdgcn_cvt_pk_fp8_f32(a, b, 0, false);
    v = __builtin_amdgcn_cvt_pk_fp8_f32(c, d, v, true);
    return (unsigned int)v;
}

// MX-scaled MFMA, fp8(e4m3) A/B, K=128, UNIT scales (E8M0 127 = 2^0):
// exact fp8 products at ~2x the non-scaled rate (m21). Layout verified
// r14/r15 (absmax 0.0): lane k = (l>>4)*32 + 0..31 per 128-k step.
#define MFMA_MX(A, B, C) \
    __builtin_amdgcn_mfma_scale_f32_16x16x128_f8f6f4((A), (B), (C), 0, 0, 0, 127, 0, 127)

// ---------------------------------------------------------------------------
// prep: w1t = ce_w1^T (fp32, coalesced CE dot); w2t8/w3t8 = fp8 N-major
// ---------------------------------------------------------------------------
__global__ __launch_bounds__(256) void prep_kernel(
    const float* __restrict__ ce_w1,   // [1024,256]
    const float* __restrict__ sf_w2,   // [256,256]
    const float* __restrict__ sf_w3,   // [256,128]
    float* __restrict__ w1t,           // [256,1024]  (may be null)
    unsigned int* __restrict__ w2t8,   // [256 n][256 k] fp8, as u32[16384]
    unsigned int* __restrict__ w3t8)   // [128 n][256 k] fp8, as u32[8192]
{
    int id = blockIdx.x * 256 + threadIdx.x;   // 0..262143
    if (w1t != nullptr) {
        int j = id >> 10, k = id & 1023;
        w1t[id] = ce_w1[k * 256 + j];
    }
    if (id < 16384) {   // w2: n = id>>6, k4 = (id&63)*4
        int n = id >> 6, k4 = (id & 63) << 2;
        w2t8[id] = pack4_fp8(sf_w2[(k4 + 0) * 256 + n], sf_w2[(k4 + 1) * 256 + n],
                             sf_w2[(k4 + 2) * 256 + n], sf_w2[(k4 + 3) * 256 + n]);
    }
    if (id < 8192) {    // w3: n = id>>6, k4 = (id&63)*4
        int n = id >> 6, k4 = (id & 63) << 2;
        w3t8[id] = pack4_fp8(sf_w3[(k4 + 0) * 128 + n], sf_w3[(k4 + 1) * 128 + n],
                             sf_w3[(k4 + 2) * 128 + n], sf_w3[(k4 + 3) * 128 + n]);
    }
}

// ---------------------------------------------------------------------------
// context encoder: one block per batch row; fp32 throughout.
// zpart[b][j] = z_c[b] @ sf_w1[2:] + sf_b1   (bias folded in)
// ---------------------------------------------------------------------------
__global__ __launch_bounds__(256) void ce_kernel(
    const float* __restrict__ features,   // [256,1024]
    const float* __restrict__ ce_w1,      // [1024,256] (fallback path)
    const float* __restrict__ w1t,        // [256,1024] or null
    const float* __restrict__ ce_b1,
    const float* __restrict__ ce_w2, const float* __restrict__ ce_b2,
    const float* __restrict__ ce_w3, const float* __restrict__ ce_b3,
    const float* __restrict__ sf_w1,      // [66,256]
    const float* __restrict__ sf_b1,
    float* __restrict__ zpart)            // [256,256]
{
    __shared__ float fs[FD];
    __shared__ float z1[HD];
    __shared__ float z2[HD / 2];
    __shared__ float zc[64];
    const int b = blockIdx.x, t = threadIdx.x;

    #pragma unroll
    for (int i = 0; i < 4; ++i) fs[t + i * 256] = features[b * FD + t + i * 256];
    __syncthreads();

    // layer 1: 1024 -> 256
    {
        float s = ce_b1[t];
        if (w1t != nullptr) {
            const float4* wr = reinterpret_cast<const float4*>(w1t + t * FD);
            #pragma unroll 4
            for (int k = 0; k < FD / 4; ++k) {
                float4 w = wr[k];
                const float4 f = *reinterpret_cast<const float4*>(&fs[k * 4]);
                s = fmaf(w.x, f.x, s);
                s = fmaf(w.y, f.y, s);
                s = fmaf(w.z, f.z, s);
                s = fmaf(w.w, f.w, s);
            }
        } else {
            #pragma unroll 8
            for (int k = 0; k < FD; ++k) s = fmaf(fs[k], ce_w1[k * 256 + t], s);
        }
        z1[t] = s > 0.f ? s : 0.f;
    }
    __syncthreads();

    // layer 2: 256 -> 128
    if (t < 128) {
        float s = ce_b2[t];
        #pragma unroll 8
        for (int k = 0; k < 256; ++k) s = fmaf(z1[k], ce_w2[k * 128 + t], s);
        z2[t] = s > 0.f ? s : 0.f;
    }
    __syncthreads();

    // layer 3: 128 -> 64 (no relu)
    if (t < 64) {
        float s = ce_b3[t];
        #pragma unroll 8
        for (int k = 0; k < 128; ++k) s = fmaf(z2[k], ce_w3[k * 64 + t], s);
        zc[t] = s;
    }
    __syncthreads();

    // zpart = zc @ sf_w1[2:] + sf_b1
    {
        float s = sf_b1[t];
        #pragma unroll 8
        for (int k = 0; k < 64; ++k) s = fmaf(zc[k], sf_w1[(2 + k) * 256 + t], s);
        zpart[b * HD + t] = s;
    }
}

// ---------------------------------------------------------------------------
// fused field MLP, fp8 MX K=128 (unit scales), weight-stationary,
// 2-deep pipeline (r7 hazard scheme), 1 barrier/phase, 2 BLOCKS/CU:
//   grid=512: block (2b+h) = batch b, tile half h (32 tiles).
//   512 thr, __launch_bounds__(512,4): cap 128 VGPR (r15 measured 108)
//   -> 16 waves/CU (4/SIMD) via co-resident blocks; 74 KB LDS/block.
//   Phase p:  GEMM1(p)+epi1 ; GEMM2(p-1)+epi2 ; build h1(p+1) ; store(p-2)
//   All intra-phase LDS read/write buffers differ mod 2 (audited = r7).
//   Register discipline from r15: one i32x8 operand live at a time,
//   acc1/acc2 lifetimes disjoint, b3/w4 loaded in epilogue2.
// ---------------------------------------------------------------------------
__global__ __launch_bounds__(512, 4) void field_kernel(
    const float* __restrict__ coords,   // [4096,2]
    const float* __restrict__ sf_w1,    // [66,256] rows 0,1 used
    const float* __restrict__ zpart,    // [256,256]
    const unsigned char* __restrict__ w2t8, // [256 n][256 k] fp8
    const float* __restrict__ sf_b2,    // [256]
    const unsigned char* __restrict__ w3t8, // [128 n][256 k] fp8
    const float* __restrict__ sf_b3,    // [128]
    const float* __restrict__ sf_w4,    // [128]
    const float* __restrict__ sf_b4,    // [1]
    float* __restrict__ out)            // [256,4096]
{
    __shared__ __attribute__((aligned(128))) unsigned char h1[2][64 * 256];  // 32 KB
    __shared__ __attribute__((aligned(128))) unsigned char h2[2][64 * 256];  // 32 KB
    __shared__ float partials[2][64][20];                                    // 10 KB

    const int bid = blockIdx.x;
    const int b = bid >> 1;            // batch row
    const int tbase = (bid & 1) * 32;  // tile half: tiles tbase .. tbase+31
    const int tid = threadIdx.x;
    const int wid = tid >> 6;
    const int lane = tid & 63;
    const int l15 = lane & 15;
    const int l4 = lane >> 4;

    // ---- resident weights (MX K=128 fragments: lane k = ks*128 + l4*32 + 0..31) ----
    const int cg1 = wid & 3;    // GEMM1 col group (64 cols)
    const int rg1 = wid >> 2;   // GEMM1 row group (32 rows)
    i32x8 b1f[2][4];
    #pragma unroll
    for (int ks = 0; ks < 2; ++ks)
        #pragma unroll
        for (int n = 0; n < 4; ++n)
            b1f[ks][n] = *reinterpret_cast<const i32x8*>(
                &w2t8[(cg1 * 64 + n * 16 + l15) * 256 + ks * 128 + l4 * 32]);

    const int cgrp = wid & 3, rhalf = wid >> 2;
    i32x8 w3f[2][2];
    #pragma unroll
    for (int ks = 0; ks < 2; ++ks)
        #pragma unroll
        for (int cb = 0; cb < 2; ++cb)
            w3f[ks][cb] = *reinterpret_cast<const i32x8*>(
                &w3t8[(cgrp * 32 + cb * 16 + l15) * 256 + ks * 128 + l4 * 32]);

    // ---- resident b2 (acc1 C-init is on the MFMA critical path) ----
    f32x4 b2r[4];
    #pragma unroll
    for (int n = 0; n < 4; ++n)
        b2r[n] = *reinterpret_cast<const f32x4*>(&sf_b2[cg1 * 64 + n * 16 + l4 * 4]);
    const float b4v = sf_b4[0];

    // ---- h1-build constants (meshgrid: xx tile-const, yy thread-invariant) ----
    const int kc = tid & 31;           // 8B chunk within row
    const int rbase = tid >> 5;        // row base 0..15 (rows rbase+16*it)
    const int kcs = (kc ^ rbase) << 3; // swizzled byte offset (row&15 == rbase)
    float zpf[8], waf[8], wbf[8];
    #pragma unroll
    for (int j = 0; j < 8; ++j) {
        zpf[j] = zpart[b * HD + kc * 8 + j];
        waf[j] = sf_w1[kc * 8 + j];
        wbf[j] = sf_w1[HD + kc * 8 + j];
    }
    float xvr[4];
    #pragma unroll
    for (int it = 0; it < 4; ++it)
        xvr[it] = coords[2 * (it * 16 + rbase) + 1];   // yy = x[row], tile-invariant

    // MX operand LDS chunk offsets: chunk = ks*16 + l4*4 + j, swizzled ^l15
    int chm[2][4];
    #pragma unroll
    for (int ks = 0; ks < 2; ++ks)
        #pragma unroll
        for (int j = 0; j < 4; ++j)
            chm[ks][j] = ((ks * 16 + l4 * 4 + j) ^ l15) << 3;

    // assemble a 32B MX operand from 4 swizzled b64 LDS reads
    auto ld32 = [&](const unsigned char* base, int row, const int* off) -> i32x8 {
        const unsigned char* p = base + row * 256;
        uint2 q0 = *reinterpret_cast<const uint2*>(p + off[0]);
        uint2 q1 = *reinterpret_cast<const uint2*>(p + off[1]);
        uint2 q2 = *reinterpret_cast<const uint2*>(p + off[2]);
        uint2 q3 = *reinterpret_cast<const uint2*>(p + off[3]);
        i32x8 r;
        r[0] = q0.x; r[1] = q0.y; r[2] = q1.x; r[3] = q1.y;
        r[4] = q2.x; r[5] = q2.y; r[6] = q3.x; r[7] = q3.y;
        return r;
    };

    auto build = [&](int p) {          // local tile p -> global tile tbase+p
        unsigned char* buf = h1[p & 1];
        float x0 = coords[(tbase + p) * 128];   // xx tile-constant
        float zc8[8];
        #pragma unroll
        for (int j = 0; j < 8; ++j) zc8[j] = fmaf(x0, waf[j], zpf[j]);
        #pragma unroll
        for (int it = 0; it < 4; ++it) {
            float xv = xvr[it];
            float s[8];
            #pragma unroll
            for (int j = 0; j < 8; ++j) {
                float v = fmaf(xv, wbf[j], zc8[j]);
                s[j] = v > 0.f ? v : 0.f;
            }
            uint2 pk;
            pk.x = pack4_fp8(s[0], s[1], s[2], s[3]);
            pk.y = pack4_fp8(s[4], s[5], s[6], s[7]);
            *reinterpret_cast<uint2*>(&buf[(it * 16 + rbase) * 256 + kcs]) = pk;
        }
    };

    auto phase = [&](int p) {
        const int pg2 = p - 1;
        const bool g1 = (p < 32);
        const bool g2 = (pg2 >= 0) && (pg2 < 32);
        const unsigned char* h1c = h1[p & 1];
        const unsigned char* h2p = h2[pg2 & 1];

        // ======== GEMM1(p) + epilogue1 (acc1 lifetime confined here) ========
        if (g1) {
            f32x4 acc1[2][4];
            #pragma unroll
            for (int m = 0; m < 2; ++m)
                #pragma unroll
                for (int n = 0; n < 4; ++n) acc1[m][n] = b2r[n];   // bias C-init

            #pragma unroll
            for (int ks = 0; ks < 2; ++ks) {
                // one operand live at a time (register discipline)
                {
                    i32x8 a = ld32(h1c, rg1 * 32 + l15, chm[ks]);
                    __builtin_amdgcn_s_setprio(1);
                    #pragma unroll
                    for (int n = 0; n < 4; ++n)
                        acc1[0][n] = MFMA_MX(b1f[ks][n], a, acc1[0][n]);
                    __builtin_amdgcn_s_setprio(0);
                }
                {
                    i32x8 a = ld32(h1c, rg1 * 32 + 16 + l15, chm[ks]);
                    __builtin_amdgcn_s_setprio(1);
                    #pragma unroll
                    for (int n = 0; n < 4; ++n)
                        acc1[1][n] = MFMA_MX(b1f[ks][n], a, acc1[1][n]);
                    __builtin_amdgcn_s_setprio(0);
                }
            }

            // epilogue1: h2 = relu(acc1) (bias pre-added) -> h2[p&1]
            unsigned char* h2c = h2[p & 1];
            #pragma unroll
            for (int n = 0; n < 4; ++n) {
                #pragma unroll
                for (int m = 0; m < 2; ++m) {
                    int row = rg1 * 32 + m * 16 + l15;
                    int chunk = cg1 * 8 + n * 2 + (l4 >> 1);
                    float x0 = fmaxf(acc1[m][n][0], 0.f);
                    float x1 = fmaxf(acc1[m][n][1], 0.f);
                    float x2 = fmaxf(acc1[m][n][2], 0.f);
                    float x3 = fmaxf(acc1[m][n][3], 0.f);
                    *reinterpret_cast<unsigned int*>(
                        &h2c[row * 256 + ((chunk ^ (row & 15)) << 3) + (l4 & 1) * 4]) =
                        pack4_fp8(x0, x1, x2, x3);
                }
            }
        }

        // ======== GEMM2(p-1) + epilogue2 (acc2 lifetime confined here) ========
        if (g2) {
            f32x4 acc2[2][2] = {};   // zero init; b3 added in epilogue
            #pragma unroll
            for (int ks = 0; ks < 2; ++ks) {
                {
                    i32x8 hb = ld32(h2p, rhalf * 32 + l15, chm[ks]);
                    __builtin_amdgcn_s_setprio(1);
                    #pragma unroll
                    for (int cb = 0; cb < 2; ++cb)
                        acc2[0][cb] = MFMA_MX(w3f[ks][cb], hb, acc2[0][cb]);
                    __builtin_amdgcn_s_setprio(0);
                }
                {
                    i32x8 hb = ld32(h2p, rhalf * 32 + 16 + l15, chm[ks]);
                    __builtin_amdgcn_s_setprio(1);
                    #pragma unroll
                    for (int cb = 0; cb < 2; ++cb)
                        acc2[1][cb] = MFMA_MX(w3f[ks][cb], hb, acc2[1][cb]);
                    __builtin_amdgcn_s_setprio(0);
                }
            }

            // epilogue2: b3/w4 loaded here (short live ranges, L1-hot)
            #pragma unroll
            for (int rb = 0; rb < 2; ++rb) {
                float pp = 0.f;
                #pragma unroll
                for (int cb = 0; cb < 2; ++cb) {
                    f32x4 b3v = *reinterpret_cast<const f32x4*>(&sf_b3[cgrp * 32 + cb * 16 + l4 * 4]);
                    f32x4 w4v = *reinterpret_cast<const f32x4*>(&sf_w4[cgrp * 32 + cb * 16 + l4 * 4]);
                    #pragma unroll
                    for (int i = 0; i < 4; ++i) {
                        float v = fmaxf(acc2[rb][cb][i] + b3v[i], 0.f);
                        pp = fmaf(v, w4v[i], pp);
                    }
                }
                partials[pg2 & 1][rhalf * 32 + rb * 16 + l15][cgrp * 4 + l4] = pp;
            }
        }

        // build h1 for tile p+1 (read next phase, after the barrier)
        if (p + 1 < 32) build(p + 1);

        // final store for tile p-2 (partials written last phase)
        const int tf = p - 2;
        if (tf >= 0 && tid < 64) {
            const f32x4* pr = reinterpret_cast<const f32x4*>(&partials[tf & 1][tid][0]);
            f32x4 ss = pr[0] + pr[1] + pr[2] + pr[3];
            float s = ss[0] + ss[1] + ss[2] + ss[3] + b4v;
            out[b * GG + (tbase + tf) * 64 + tid] = 1.f / (1.f + __expf(-s));
        }
    };

    // prologue: tile 0
    build(0);
    __syncthreads();

    #pragma unroll 1
    for (int p = 0; p < 34; ++p) {
        phase(p);
        __syncthreads();
    }
}

// ---------------------------------------------------------------------------
extern "C" void kernel_launch(void* const* d_in, const int* in_sizes, int n_in,
                              void* d_out, int out_size, void* d_ws, size_t ws_size,
                              hipStream_t stream)
{
    const float* features = (const float*)d_in[0];
    const float* coords   = (const float*)d_in[1];
    const float* ce_w1 = (const float*)d_in[2];
    const float* ce_b1 = (const float*)d_in[3];
    const float* ce_w2 = (const float*)d_in[4];
    const float* ce_b2 = (const float*)d_in[5];
    const float* ce_w3 = (const float*)d_in[6];
    const float* ce_b3 = (const float*)d_in[7];
    const float* sf_w1 = (const float*)d_in[8];
    const float* sf_b1 = (const float*)d_in[9];
    const float* sf_w2 = (const float*)d_in[10];
    const float* sf_b2 = (const float*)d_in[11];
    const float* sf_w3 = (const float*)d_in[12];
    const float* sf_b3 = (const float*)d_in[13];
    const float* sf_w4 = (const float*)d_in[14];
    const float* sf_b4 = (const float*)d_in[15];
    float* out = (float*)d_out;

    char* ws = (char*)d_ws;
    float*        zpart = (float*)ws;                             // 256 KB
    unsigned int* w2t8  = (unsigned int*)(ws + 262144);           //  64 KB
    unsigned int* w3t8  = (unsigned int*)(ws + 262144 + 65536);   //  32 KB
    float*        w1t   = (float*)(ws + 262144 + 65536 + 32768);  //   1 MB (optional)
    const size_t need_w1t = (size_t)(262144 + 65536 + 32768) + (size_t)FD * HD * 4;
    float* w1t_ptr = (ws_size >= need_w1t) ? w1t : nullptr;

    hipLaunchKernelGGL(prep_kernel, dim3(1024), dim3(256), 0, stream,
                       ce_w1, sf_w2, sf_w3, w1t_ptr, w2t8, w3t8);
    hipLaunchKernelGGL(ce_kernel, dim3(256), dim3(256), 0, stream,
                       features, ce_w1, w1t_ptr, ce_b1, ce_w2, ce_b2, ce_w3, ce_b3,
                       sf_w1, sf_b1, zpart);
    hipLaunchKernelGGL(field_kernel, dim3(512), dim3(512), 0, stream,
                       coords, sf_w1, zpart,
                       (const unsigned char*)w2t8, sf_b2,
                       (const unsigned char*)w3t8, sf_b3, sf_w4, sf_b4, out);
}

// Round 18
// 180.595 us; speedup vs baseline: 3.2950x; 3.2950x over previous
//
#include <hip/hip_runtime.h>
#include <hip/hip_bf16.h>

typedef __bf16 bf16_t;
typedef __attribute__((ext_vector_type(4))) float f32x4;
typedef __attribute__((ext_vector_type(8))) int i32x8;

#define FD 1024
#define HD 256
#define GG 4096

// pack 4 f32 -> 4 OCP e4m3 bytes (v_cvt_pk_fp8_f32, gfx950 = OCP)
__device__ inline unsigned int pack4_fp8(float a, float b, float c, float d) {
    int v = __builtin_amdgcn_cvt_pk_fp8_f32(a, b, 0, false);
    v = __builtin_amdgcn_cvt_pk_fp8_f32(c, d, v, true);
    return (unsigned int)v;
}

// MX-scaled MFMA, fp8(e4m3) A/B, K=128, UNIT scales (E8M0 127 = 2^0):
// exact fp8 products at ~2x the non-scaled rate (m21). Layout verified
// r14/r15 (absmax 0.0): lane k = (l>>4)*32 + 0..31 per 128-k step.
#define MFMA_MX(A, B, C) \
    __builtin_amdgcn_mfma_scale_f32_16x16x128_f8f6f4((A), (B), (C), 0, 0, 0, 127, 0, 127)

// ---------------------------------------------------------------------------
// prep: w1t = ce_w1^T (fp32, coalesced CE dot); w2t8/w3t8 = fp8 N-major
// ---------------------------------------------------------------------------
__global__ __launch_bounds__(256) void prep_kernel(
    const float* __restrict__ ce_w1,   // [1024,256]
    const float* __restrict__ sf_w2,   // [256,256]
    const float* __restrict__ sf_w3,   // [256,128]
    float* __restrict__ w1t,           // [256,1024]  (may be null)
    unsigned int* __restrict__ w2t8,   // [256 n][256 k] fp8, as u32[16384]
    unsigned int* __restrict__ w3t8)   // [128 n][256 k] fp8, as u32[8192]
{
    int id = blockIdx.x * 256 + threadIdx.x;   // 0..262143
    if (w1t != nullptr) {
        int j = id >> 10, k = id & 1023;
        w1t[id] = ce_w1[k * 256 + j];
    }
    if (id < 16384) {   // w2: n = id>>6, k4 = (id&63)*4
        int n = id >> 6, k4 = (id & 63) << 2;
        w2t8[id] = pack4_fp8(sf_w2[(k4 + 0) * 256 + n], sf_w2[(k4 + 1) * 256 + n],
                             sf_w2[(k4 + 2) * 256 + n], sf_w2[(k4 + 3) * 256 + n]);
    }
    if (id < 8192) {    // w3: n = id>>6, k4 = (id&63)*4
        int n = id >> 6, k4 = (id & 63) << 2;
        w3t8[id] = pack4_fp8(sf_w3[(k4 + 0) * 128 + n], sf_w3[(k4 + 1) * 128 + n],
                             sf_w3[(k4 + 2) * 128 + n], sf_w3[(k4 + 3) * 128 + n]);
    }
}

// ---------------------------------------------------------------------------
// context encoder: one block per batch row; fp32 throughout.
// zpart[b][j] = z_c[b] @ sf_w1[2:] + sf_b1   (bias folded in)
// ---------------------------------------------------------------------------
__global__ __launch_bounds__(256) void ce_kernel(
    const float* __restrict__ features,   // [256,1024]
    const float* __restrict__ ce_w1,      // [1024,256] (fallback path)
    const float* __restrict__ w1t,        // [256,1024] or null
    const float* __restrict__ ce_b1,
    const float* __restrict__ ce_w2, const float* __restrict__ ce_b2,
    const float* __restrict__ ce_w3, const float* __restrict__ ce_b3,
    const float* __restrict__ sf_w1,      // [66,256]
    const float* __restrict__ sf_b1,
    float* __restrict__ zpart)            // [256,256]
{
    __shared__ float fs[FD];
    __shared__ float z1[HD];
    __shared__ float z2[HD / 2];
    __shared__ float zc[64];
    const int b = blockIdx.x, t = threadIdx.x;

    #pragma unroll
    for (int i = 0; i < 4; ++i) fs[t + i * 256] = features[b * FD + t + i * 256];
    __syncthreads();

    // layer 1: 1024 -> 256
    {
        float s = ce_b1[t];
        if (w1t != nullptr) {
            const float4* wr = reinterpret_cast<const float4*>(w1t + t * FD);
            #pragma unroll 4
            for (int k = 0; k < FD / 4; ++k) {
                float4 w = wr[k];
                const float4 f = *reinterpret_cast<const float4*>(&fs[k * 4]);
                s = fmaf(w.x, f.x, s);
                s = fmaf(w.y, f.y, s);
                s = fmaf(w.z, f.z, s);
                s = fmaf(w.w, f.w, s);
            }
        } else {
            #pragma unroll 8
            for (int k = 0; k < FD; ++k) s = fmaf(fs[k], ce_w1[k * 256 + t], s);
        }
        z1[t] = s > 0.f ? s : 0.f;
    }
    __syncthreads();

    // layer 2: 256 -> 128
    if (t < 128) {
        float s = ce_b2[t];
        #pragma unroll 8
        for (int k = 0; k < 256; ++k) s = fmaf(z1[k], ce_w2[k * 128 + t], s);
        z2[t] = s > 0.f ? s : 0.f;
    }
    __syncthreads();

    // layer 3: 128 -> 64 (no relu)
    if (t < 64) {
        float s = ce_b3[t];
        #pragma unroll 8
        for (int k = 0; k < 128; ++k) s = fmaf(z2[k], ce_w3[k * 64 + t], s);
        zc[t] = s;
    }
    __syncthreads();

    // zpart = zc @ sf_w1[2:] + sf_b1
    {
        float s = sf_b1[t];
        #pragma unroll 8
        for (int k = 0; k < 64; ++k) s = fmaf(zc[k], sf_w1[(2 + k) * 256 + t], s);
        zpart[b * HD + t] = s;
    }
}

// ---------------------------------------------------------------------------
// fused field MLP, fp8 MX K=128 (unit scales), weight-stationary,
// 2-deep pipeline (r7 hazard scheme), 1 barrier/phase, 2 blocks/CU target:
//   grid=512: block (2b+h) = batch b, tile half h (32 tiles).
//   512 thr, __launch_bounds__(512,2) -- NOT (512,4): 2nd arg is min
//   waves/SIMD; 4 forced a 64-VGPR cap and 1.9 GB of spill (r17).
//   This body measured 108 VGPR (r15); 74 KB LDS -> 2 blocks/CU co-resident
//   if the unified register total stays <= 128.
//   Phase p:  GEMM1(p)+epi1 ; GEMM2(p-1)+epi2 ; build h1(p+1) ; store(p-2)
//   All intra-phase LDS read/write buffers differ mod 2 (audited = r7).
//   Register discipline from r15: one i32x8 operand live at a time,
//   acc1/acc2 lifetimes disjoint, b3/w4 loaded in epilogue2.
// ---------------------------------------------------------------------------
__global__ __launch_bounds__(512, 2) void field_kernel(
    const float* __restrict__ coords,   // [4096,2]
    const float* __restrict__ sf_w1,    // [66,256] rows 0,1 used
    const float* __restrict__ zpart,    // [256,256]
    const unsigned char* __restrict__ w2t8, // [256 n][256 k] fp8
    const float* __restrict__ sf_b2,    // [256]
    const unsigned char* __restrict__ w3t8, // [128 n][256 k] fp8
    const float* __restrict__ sf_b3,    // [128]
    const float* __restrict__ sf_w4,    // [128]
    const float* __restrict__ sf_b4,    // [1]
    float* __restrict__ out)            // [256,4096]
{
    __shared__ __attribute__((aligned(128))) unsigned char h1[2][64 * 256];  // 32 KB
    __shared__ __attribute__((aligned(128))) unsigned char h2[2][64 * 256];  // 32 KB
    __shared__ float partials[2][64][20];                                    // 10 KB

    const int bid = blockIdx.x;
    const int b = bid >> 1;            // batch row
    const int tbase = (bid & 1) * 32;  // tile half: tiles tbase .. tbase+31
    const int tid = threadIdx.x;
    const int wid = tid >> 6;
    const int lane = tid & 63;
    const int l15 = lane & 15;
    const int l4 = lane >> 4;

    // ---- resident weights (MX K=128 fragments: lane k = ks*128 + l4*32 + 0..31) ----
    const int cg1 = wid & 3;    // GEMM1 col group (64 cols)
    const int rg1 = wid >> 2;   // GEMM1 row group (32 rows)
    i32x8 b1f[2][4];
    #pragma unroll
    for (int ks = 0; ks < 2; ++ks)
        #pragma unroll
        for (int n = 0; n < 4; ++n)
            b1f[ks][n] = *reinterpret_cast<const i32x8*>(
                &w2t8[(cg1 * 64 + n * 16 + l15) * 256 + ks * 128 + l4 * 32]);

    const int cgrp = wid & 3, rhalf = wid >> 2;
    i32x8 w3f[2][2];
    #pragma unroll
    for (int ks = 0; ks < 2; ++ks)
        #pragma unroll
        for (int cb = 0; cb < 2; ++cb)
            w3f[ks][cb] = *reinterpret_cast<const i32x8*>(
                &w3t8[(cgrp * 32 + cb * 16 + l15) * 256 + ks * 128 + l4 * 32]);

    // ---- resident b2 (acc1 C-init is on the MFMA critical path) ----
    f32x4 b2r[4];
    #pragma unroll
    for (int n = 0; n < 4; ++n)
        b2r[n] = *reinterpret_cast<const f32x4*>(&sf_b2[cg1 * 64 + n * 16 + l4 * 4]);
    const float b4v = sf_b4[0];

    // ---- h1-build constants (meshgrid: xx tile-const, yy thread-invariant) ----
    const int kc = tid & 31;           // 8B chunk within row
    const int rbase = tid >> 5;        // row base 0..15 (rows rbase+16*it)
    const int kcs = (kc ^ rbase) << 3; // swizzled byte offset (row&15 == rbase)
    float zpf[8], waf[8], wbf[8];
    #pragma unroll
    for (int j = 0; j < 8; ++j) {
        zpf[j] = zpart[b * HD + kc * 8 + j];
        waf[j] = sf_w1[kc * 8 + j];
        wbf[j] = sf_w1[HD + kc * 8 + j];
    }
    float xvr[4];
    #pragma unroll
    for (int it = 0; it < 4; ++it)
        xvr[it] = coords[2 * (it * 16 + rbase) + 1];   // yy = x[row], tile-invariant

    // MX operand LDS chunk offsets: chunk = ks*16 + l4*4 + j, swizzled ^l15
    int chm[2][4];
    #pragma unroll
    for (int ks = 0; ks < 2; ++ks)
        #pragma unroll
        for (int j = 0; j < 4; ++j)
            chm[ks][j] = ((ks * 16 + l4 * 4 + j) ^ l15) << 3;

    // assemble a 32B MX operand from 4 swizzled b64 LDS reads
    auto ld32 = [&](const unsigned char* base, int row, const int* off) -> i32x8 {
        const unsigned char* p = base + row * 256;
        uint2 q0 = *reinterpret_cast<const uint2*>(p + off[0]);
        uint2 q1 = *reinterpret_cast<const uint2*>(p + off[1]);
        uint2 q2 = *reinterpret_cast<const uint2*>(p + off[2]);
        uint2 q3 = *reinterpret_cast<const uint2*>(p + off[3]);
        i32x8 r;
        r[0] = q0.x; r[1] = q0.y; r[2] = q1.x; r[3] = q1.y;
        r[4] = q2.x; r[5] = q2.y; r[6] = q3.x; r[7] = q3.y;
        return r;
    };

    auto build = [&](int p) {          // local tile p -> global tile tbase+p
        unsigned char* buf = h1[p & 1];
        float x0 = coords[(tbase + p) * 128];   // xx tile-constant
        float zc8[8];
        #pragma unroll
        for (int j = 0; j < 8; ++j) zc8[j] = fmaf(x0, waf[j], zpf[j]);
        #pragma unroll
        for (int it = 0; it < 4; ++it) {
            float xv = xvr[it];
            float s[8];
            #pragma unroll
            for (int j = 0; j < 8; ++j) {
                float v = fmaf(xv, wbf[j], zc8[j]);
                s[j] = v > 0.f ? v : 0.f;
            }
            uint2 pk;
            pk.x = pack4_fp8(s[0], s[1], s[2], s[3]);
            pk.y = pack4_fp8(s[4], s[5], s[6], s[7]);
            *reinterpret_cast<uint2*>(&buf[(it * 16 + rbase) * 256 + kcs]) = pk;
        }
    };

    auto phase = [&](int p) {
        const int pg2 = p - 1;
        const bool g1 = (p < 32);
        const bool g2 = (pg2 >= 0) && (pg2 < 32);
        const unsigned char* h1c = h1[p & 1];
        const unsigned char* h2p = h2[pg2 & 1];

        // ======== GEMM1(p) + epilogue1 (acc1 lifetime confined here) ========
        if (g1) {
            f32x4 acc1[2][4];
            #pragma unroll
            for (int m = 0; m < 2; ++m)
                #pragma unroll
                for (int n = 0; n < 4; ++n) acc1[m][n] = b2r[n];   // bias C-init

            #pragma unroll
            for (int ks = 0; ks < 2; ++ks) {
                // one operand live at a time (register discipline)
                {
                    i32x8 a = ld32(h1c, rg1 * 32 + l15, chm[ks]);
                    __builtin_amdgcn_s_setprio(1);
                    #pragma unroll
                    for (int n = 0; n < 4; ++n)
                        acc1[0][n] = MFMA_MX(b1f[ks][n], a, acc1[0][n]);
                    __builtin_amdgcn_s_setprio(0);
                }
                {
                    i32x8 a = ld32(h1c, rg1 * 32 + 16 + l15, chm[ks]);
                    __builtin_amdgcn_s_setprio(1);
                    #pragma unroll
                    for (int n = 0; n < 4; ++n)
                        acc1[1][n] = MFMA_MX(b1f[ks][n], a, acc1[1][n]);
                    __builtin_amdgcn_s_setprio(0);
                }
            }

            // epilogue1: h2 = relu(acc1) (bias pre-added) -> h2[p&1]
            unsigned char* h2c = h2[p & 1];
            #pragma unroll
            for (int n = 0; n < 4; ++n) {
                #pragma unroll
                for (int m = 0; m < 2; ++m) {
                    int row = rg1 * 32 + m * 16 + l15;
                    int chunk = cg1 * 8 + n * 2 + (l4 >> 1);
                    float x0 = fmaxf(acc1[m][n][0], 0.f);
                    float x1 = fmaxf(acc1[m][n][1], 0.f);
                    float x2 = fmaxf(acc1[m][n][2], 0.f);
                    float x3 = fmaxf(acc1[m][n][3], 0.f);
                    *reinterpret_cast<unsigned int*>(
                        &h2c[row * 256 + ((chunk ^ (row & 15)) << 3) + (l4 & 1) * 4]) =
                        pack4_fp8(x0, x1, x2, x3);
                }
            }
        }

        // ======== GEMM2(p-1) + epilogue2 (acc2 lifetime confined here) ========
        if (g2) {
            f32x4 acc2[2][2] = {};   // zero init; b3 added in epilogue
            #pragma unroll
            for (int ks = 0; ks < 2; ++ks) {
                {
                    i32x8 hb = ld32(h2p, rhalf * 32 + l15, chm[ks]);
                    __builtin_amdgcn_s_setprio(1);
                    #pragma unroll
                    for (int cb = 0; cb < 2; ++cb)
                        acc2[0][cb] = MFMA_MX(w3f[ks][cb], hb, acc2[0][cb]);
                    __builtin_amdgcn_s_setprio(0);
                }
                {
                    i32x8 hb = ld32(h2p, rhalf * 32 + 16 + l15, chm[ks]);
                    __builtin_amdgcn_s_setprio(1);
                    #pragma unroll
                    for (int cb = 0; cb < 2; ++cb)
                        acc2[1][cb] = MFMA_MX(w3f[ks][cb], hb, acc2[1][cb]);
                    __builtin_amdgcn_s_setprio(0);
                }
            }

            // epilogue2: b3/w4 loaded here (short live ranges, L1-hot)
            #pragma unroll
            for (int rb = 0; rb < 2; ++rb) {
                float pp = 0.f;
                #pragma unroll
                for (int cb = 0; cb < 2; ++cb) {
                    f32x4 b3v = *reinterpret_cast<const f32x4*>(&sf_b3[cgrp * 32 + cb * 16 + l4 * 4]);
                    f32x4 w4v = *reinterpret_cast<const f32x4*>(&sf_w4[cgrp * 32 + cb * 16 + l4 * 4]);
                    #pragma unroll
                    for (int i = 0; i < 4; ++i) {
                        float v = fmaxf(acc2[rb][cb][i] + b3v[i], 0.f);
                        pp = fmaf(v, w4v[i], pp);
                    }
                }
                partials[pg2 & 1][rhalf * 32 + rb * 16 + l15][cgrp * 4 + l4] = pp;
            }
        }

        // build h1 for tile p+1 (read next phase, after the barrier)
        if (p + 1 < 32) build(p + 1);

        // final store for tile p-2 (partials written last phase)
        const int tf = p - 2;
        if (tf >= 0 && tid < 64) {
            const f32x4* pr = reinterpret_cast<const f32x4*>(&partials[tf & 1][tid][0]);
            f32x4 ss = pr[0] + pr[1] + pr[2] + pr[3];
            float s = ss[0] + ss[1] + ss[2] + ss[3] + b4v;
            out[b * GG + (tbase + tf) * 64 + tid] = 1.f / (1.f + __expf(-s));
        }
    };

    // prologue: tile 0
    build(0);
    __syncthreads();

    #pragma unroll 1
    for (int p = 0; p < 34; ++p) {
        phase(p);
        __syncthreads();
    }
}

// ---------------------------------------------------------------------------
extern "C" void kernel_launch(void* const* d_in, const int* in_sizes, int n_in,
                              void* d_out, int out_size, void* d_ws, size_t ws_size,
                              hipStream_t stream)
{
    const float* features = (const float*)d_in[0];
    const float* coords   = (const float*)d_in[1];
    const float* ce_w1 = (const float*)d_in[2];
    const float* ce_b1 = (const float*)d_in[3];
    const float* ce_w2 = (const float*)d_in[4];
    const float* ce_b2 = (const float*)d_in[5];
    const float* ce_w3 = (const float*)d_in[6];
    const float* ce_b3 = (const float*)d_in[7];
    const float* sf_w1 = (const float*)d_in[8];
    const float* sf_b1 = (const float*)d_in[9];
    const float* sf_w2 = (const float*)d_in[10];
    const float* sf_b2 = (const float*)d_in[11];
    const float* sf_w3 = (const float*)d_in[12];
    const float* sf_b3 = (const float*)d_in[13];
    const float* sf_w4 = (const float*)d_in[14];
    const float* sf_b4 = (const float*)d_in[15];
    float* out = (float*)d_out;

    char* ws = (char*)d_ws;
    float*        zpart = (float*)ws;                             // 256 KB
    unsigned int* w2t8  = (unsigned int*)(ws + 262144);           //  64 KB
    unsigned int* w3t8  = (unsigned int*)(ws + 262144 + 65536);   //  32 KB
    float*        w1t   = (float*)(ws + 262144 + 65536 + 32768);  //   1 MB (optional)
    const size_t need_w1t = (size_t)(262144 + 65536 + 32768) + (size_t)FD * HD * 4;
    float* w1t_ptr = (ws_size >= need_w1t) ? w1t : nullptr;

    hipLaunchKernelGGL(prep_kernel, dim3(1024), dim3(256), 0, stream,
                       ce_w1, sf_w2, sf_w3, w1t_ptr, w2t8, w3t8);
    hipLaunchKernelGGL(ce_kernel, dim3(256), dim3(256), 0, stream,
                       features, ce_w1, w1t_ptr, ce_b1, ce_w2, ce_b2, ce_w3, ce_b3,
                       sf_w1, sf_b1, zpart);
    hipLaunchKernelGGL(field_kernel, dim3(512), dim3(512), 0, stream,
                       coords, sf_w1, zpart,
                       (const unsigned char*)w2t8, sf_b2,
                       (const unsigned char*)w3t8, sf_b3, sf_w4, sf_b4, out);
}

// Round 19
// 165.423 us; speedup vs baseline: 3.5972x; 1.0917x over previous
//
#include <hip/hip_runtime.h>
#include <hip/hip_bf16.h>

typedef __bf16 bf16_t;
typedef __attribute__((ext_vector_type(4))) float f32x4;
typedef __attribute__((ext_vector_type(8))) int i32x8;

#define FD 1024
#define HD 256
#define GG 4096
#define HSTR 272   // padded LDS row stride (bytes): bank = 4*(row&7)+8*l4, 2-way max

// pack 4 f32 -> 4 OCP e4m3 bytes (v_cvt_pk_fp8_f32, gfx950 = OCP)
__device__ inline unsigned int pack4_fp8(float a, float b, float c, float d) {
    int v = __builtin_amdgcn_cvt_pk_fp8_f32(a, b, 0, false);
    v = __builtin_amdgcn_cvt_pk_fp8_f32(c, d, v, true);
    return (unsigned int)v;
}

// MX-scaled MFMA, fp8(e4m3) A/B, K=128, UNIT scales (E8M0 127 = 2^0):
// exact fp8 products at ~2x the non-scaled rate (m21). Layout verified
// r14/r15 (absmax 0.0): lane k = (l>>4)*32 + 0..31 per 128-k step.
#define MFMA_MX(A, B, C) \
    __builtin_amdgcn_mfma_scale_f32_16x16x128_f8f6f4((A), (B), (C), 0, 0, 0, 127, 0, 127)

// ---------------------------------------------------------------------------
// prep: w1t = ce_w1^T (fp32, coalesced CE dot); w2t8/w3t8 = fp8 N-major
// ---------------------------------------------------------------------------
__global__ __launch_bounds__(256) void prep_kernel(
    const float* __restrict__ ce_w1,   // [1024,256]
    const float* __restrict__ sf_w2,   // [256,256]
    const float* __restrict__ sf_w3,   // [256,128]
    float* __restrict__ w1t,           // [256,1024]  (may be null)
    unsigned int* __restrict__ w2t8,   // [256 n][256 k] fp8, as u32[16384]
    unsigned int* __restrict__ w3t8)   // [128 n][256 k] fp8, as u32[8192]
{
    int id = blockIdx.x * 256 + threadIdx.x;   // 0..262143
    if (w1t != nullptr) {
        int j = id >> 10, k = id & 1023;
        w1t[id] = ce_w1[k * 256 + j];
    }
    if (id < 16384) {   // w2: n = id>>6, k4 = (id&63)*4
        int n = id >> 6, k4 = (id & 63) << 2;
        w2t8[id] = pack4_fp8(sf_w2[(k4 + 0) * 256 + n], sf_w2[(k4 + 1) * 256 + n],
                             sf_w2[(k4 + 2) * 256 + n], sf_w2[(k4 + 3) * 256 + n]);
    }
    if (id < 8192) {    // w3: n = id>>6, k4 = (id&63)*4
        int n = id >> 6, k4 = (id & 63) << 2;
        w3t8[id] = pack4_fp8(sf_w3[(k4 + 0) * 128 + n], sf_w3[(k4 + 1) * 128 + n],
                             sf_w3[(k4 + 2) * 128 + n], sf_w3[(k4 + 3) * 128 + n]);
    }
}

// ---------------------------------------------------------------------------
// context encoder: one block per batch row; fp32 throughout.
// zpart[b][j] = z_c[b] @ sf_w1[2:] + sf_b1   (bias folded in)
// ---------------------------------------------------------------------------
__global__ __launch_bounds__(256) void ce_kernel(
    const float* __restrict__ features,   // [256,1024]
    const float* __restrict__ ce_w1,      // [1024,256] (fallback path)
    const float* __restrict__ w1t,        // [256,1024] or null
    const float* __restrict__ ce_b1,
    const float* __restrict__ ce_w2, const float* __restrict__ ce_b2,
    const float* __restrict__ ce_w3, const float* __restrict__ ce_b3,
    const float* __restrict__ sf_w1,      // [66,256]
    const float* __restrict__ sf_b1,
    float* __restrict__ zpart)            // [256,256]
{
    __shared__ float fs[FD];
    __shared__ float z1[HD];
    __shared__ float z2[HD / 2];
    __shared__ float zc[64];
    const int b = blockIdx.x, t = threadIdx.x;

    #pragma unroll
    for (int i = 0; i < 4; ++i) fs[t + i * 256] = features[b * FD + t + i * 256];
    __syncthreads();

    // layer 1: 1024 -> 256
    {
        float s = ce_b1[t];
        if (w1t != nullptr) {
            const float4* wr = reinterpret_cast<const float4*>(w1t + t * FD);
            #pragma unroll 4
            for (int k = 0; k < FD / 4; ++k) {
                float4 w = wr[k];
                const float4 f = *reinterpret_cast<const float4*>(&fs[k * 4]);
                s = fmaf(w.x, f.x, s);
                s = fmaf(w.y, f.y, s);
                s = fmaf(w.z, f.z, s);
                s = fmaf(w.w, f.w, s);
            }
        } else {
            #pragma unroll 8
            for (int k = 0; k < FD; ++k) s = fmaf(fs[k], ce_w1[k * 256 + t], s);
        }
        z1[t] = s > 0.f ? s : 0.f;
    }
    __syncthreads();

    // layer 2: 256 -> 128
    if (t < 128) {
        float s = ce_b2[t];
        #pragma unroll 8
        for (int k = 0; k < 256; ++k) s = fmaf(z1[k], ce_w2[k * 128 + t], s);
        z2[t] = s > 0.f ? s : 0.f;
    }
    __syncthreads();

    // layer 3: 128 -> 64 (no relu)
    if (t < 64) {
        float s = ce_b3[t];
        #pragma unroll 8
        for (int k = 0; k < 128; ++k) s = fmaf(z2[k], ce_w3[k * 64 + t], s);
        zc[t] = s;
    }
    __syncthreads();

    // zpart = zc @ sf_w1[2:] + sf_b1
    {
        float s = sf_b1[t];
        #pragma unroll 8
        for (int k = 0; k < 64; ++k) s = fmaf(zc[k], sf_w1[(2 + k) * 256 + t], s);
        zpart[b * HD + t] = s;
    }
}

// ---------------------------------------------------------------------------
// fused field MLP, fp8 MX K=128 (unit scales), weight-stationary, 4-deep
// pipeline, 1 barrier/2 tiles (r15 structure), PADDED-LINEAR LDS layout:
//   row stride 272 B (no XOR swizzle) -> each lane's 32B MFMA operand is
//   CONTIGUOUS: 2 x ds_read_b128 from one address (+16 imm), no per-chunk
//   address math. bank = 4*(row&7)+8*l4 -> <=2-way everywhere (free, m136).
//   grid=256 (1 block/CU), 512 thr (8 waves, 2/SIMD -- unified-VGPR cap).
//   Sub-phase t:  GEMM1(t)+epi1 ; GEMM2(t-2)+epi2 ; build h1(t+2) ; store(t-4)
//   Register discipline from r15: one i32x8 operand live at a time,
//   acc1/acc2 lifetimes disjoint, b3/w4 loaded in epilogue2.
// ---------------------------------------------------------------------------
__global__ __launch_bounds__(512, 2) void field_kernel(
    const float* __restrict__ coords,   // [4096,2]
    const float* __restrict__ sf_w1,    // [66,256] rows 0,1 used
    const float* __restrict__ zpart,    // [256,256]
    const unsigned char* __restrict__ w2t8, // [256 n][256 k] fp8
    const float* __restrict__ sf_b2,    // [256]
    const unsigned char* __restrict__ w3t8, // [128 n][256 k] fp8
    const float* __restrict__ sf_b3,    // [128]
    const float* __restrict__ sf_w4,    // [128]
    const float* __restrict__ sf_b4,    // [1]
    float* __restrict__ out)            // [256,4096]
{
    __shared__ __attribute__((aligned(128))) unsigned char h1[4][64 * HSTR];  // 68 KB
    __shared__ __attribute__((aligned(128))) unsigned char h2[4][64 * HSTR];  // 68 KB
    __shared__ float partials[4][64][20];                                     // 20 KB

    const int b = blockIdx.x;
    const int tid = threadIdx.x;
    const int wid = tid >> 6;
    const int lane = tid & 63;
    const int l15 = lane & 15;
    const int l4 = lane >> 4;
    const int koff = l4 * 32;          // lane's 32B k-slice within a 128-k step

    // ---- resident weights (MX K=128 fragments: lane k = ks*128 + l4*32 + 0..31) ----
    const int cg1 = wid & 3;    // GEMM1 col group (64 cols)
    const int rg1 = wid >> 2;   // GEMM1 row group (32 rows)
    i32x8 b1f[2][4];
    #pragma unroll
    for (int ks = 0; ks < 2; ++ks)
        #pragma unroll
        for (int n = 0; n < 4; ++n)
            b1f[ks][n] = *reinterpret_cast<const i32x8*>(
                &w2t8[(cg1 * 64 + n * 16 + l15) * 256 + ks * 128 + koff]);

    const int cgrp = wid & 3, rhalf = wid >> 2;
    i32x8 w3f[2][2];
    #pragma unroll
    for (int ks = 0; ks < 2; ++ks)
        #pragma unroll
        for (int cb = 0; cb < 2; ++cb)
            w3f[ks][cb] = *reinterpret_cast<const i32x8*>(
                &w3t8[(cgrp * 32 + cb * 16 + l15) * 256 + ks * 128 + koff]);

    // ---- resident b2 (acc1 C-init is on the MFMA critical path) ----
    f32x4 b2r[4];
    #pragma unroll
    for (int n = 0; n < 4; ++n)
        b2r[n] = *reinterpret_cast<const f32x4*>(&sf_b2[cg1 * 64 + n * 16 + l4 * 4]);
    const float b4v = sf_b4[0];

    // ---- h1-build constants (meshgrid: xx tile-const, yy thread-invariant) ----
    const int kc = tid & 31;           // 8B chunk within row (linear, no swizzle)
    const int rbase = tid >> 5;        // row base 0..15 (rows rbase+16*it)
    float zpf[8], waf[8], wbf[8];
    #pragma unroll
    for (int j = 0; j < 8; ++j) {
        zpf[j] = zpart[b * HD + kc * 8 + j];
        waf[j] = sf_w1[kc * 8 + j];
        wbf[j] = sf_w1[HD + kc * 8 + j];
    }
    float xvr[4];
    #pragma unroll
    for (int it = 0; it < 4; ++it)
        xvr[it] = coords[2 * (it * 16 + rbase) + 1];   // yy = x[row], tile-invariant

    // contiguous 32B LDS operand: 2 x 16B (compiler emits 2 ds_read_b128)
    auto ld32 = [&](const unsigned char* p) -> i32x8 {
        uint4 a = *reinterpret_cast<const uint4*>(p);
        uint4 c = *reinterpret_cast<const uint4*>(p + 16);
        i32x8 r;
        r[0] = a.x; r[1] = a.y; r[2] = a.z; r[3] = a.w;
        r[4] = c.x; r[5] = c.y; r[6] = c.z; r[7] = c.w;
        return r;
    };

    auto build = [&](int t) {
        unsigned char* buf = h1[t & 3];
        float x0 = coords[t * 128];    // xx tile-constant
        float zc8[8];
        #pragma unroll
        for (int j = 0; j < 8; ++j) zc8[j] = fmaf(x0, waf[j], zpf[j]);
        #pragma unroll
        for (int it = 0; it < 4; ++it) {
            float xv = xvr[it];
            float s[8];
            #pragma unroll
            for (int j = 0; j < 8; ++j) {
                float v = fmaf(xv, wbf[j], zc8[j]);
                s[j] = v > 0.f ? v : 0.f;
            }
            uint2 pk;
            pk.x = pack4_fp8(s[0], s[1], s[2], s[3]);
            pk.y = pack4_fp8(s[4], s[5], s[6], s[7]);
            *reinterpret_cast<uint2*>(&buf[(it * 16 + rbase) * HSTR + kc * 8]) = pk;
        }
    };

    auto subphase = [&](int t) {
        const int tg2 = t - 2;
        const bool g1 = (t < 64);
        const bool g2 = (tg2 >= 0);    // tg2 < 64 guaranteed by loop bound
        const unsigned char* h1c = h1[t & 3];
        const unsigned char* h2p = h2[tg2 & 3];

        // ======== GEMM1(t) + epilogue1 (acc1 lifetime confined here) ========
        if (g1) {
            f32x4 acc1[2][4];
            #pragma unroll
            for (int m = 0; m < 2; ++m)
                #pragma unroll
                for (int n = 0; n < 4; ++n) acc1[m][n] = b2r[n];   // bias C-init

            const unsigned char* r0 = h1c + (rg1 * 32 + l15) * HSTR + koff;
            const unsigned char* r1 = r0 + 16 * HSTR;
            #pragma unroll
            for (int ks = 0; ks < 2; ++ks) {
                // one operand live at a time (register discipline)
                {
                    i32x8 a = ld32(r0 + ks * 128);
                    __builtin_amdgcn_s_setprio(1);
                    #pragma unroll
                    for (int n = 0; n < 4; ++n)
                        acc1[0][n] = MFMA_MX(b1f[ks][n], a, acc1[0][n]);
                    __builtin_amdgcn_s_setprio(0);
                }
                {
                    i32x8 a = ld32(r1 + ks * 128);
                    __builtin_amdgcn_s_setprio(1);
                    #pragma unroll
                    for (int n = 0; n < 4; ++n)
                        acc1[1][n] = MFMA_MX(b1f[ks][n], a, acc1[1][n]);
                    __builtin_amdgcn_s_setprio(0);
                }
            }

            // epilogue1: h2 = relu(acc1) (bias pre-added) -> h2[t&3]
            unsigned char* h2c = h2[t & 3];
            #pragma unroll
            for (int n = 0; n < 4; ++n) {
                #pragma unroll
                for (int m = 0; m < 2; ++m) {
                    int row = rg1 * 32 + m * 16 + l15;
                    int col = cg1 * 64 + n * 16 + l4 * 4;
                    float x0 = fmaxf(acc1[m][n][0], 0.f);
                    float x1 = fmaxf(acc1[m][n][1], 0.f);
                    float x2 = fmaxf(acc1[m][n][2], 0.f);
                    float x3 = fmaxf(acc1[m][n][3], 0.f);
                    *reinterpret_cast<unsigned int*>(&h2c[row * HSTR + col]) =
                        pack4_fp8(x0, x1, x2, x3);
                }
            }
        }

        // ======== GEMM2(t-2) + epilogue2 (acc2 lifetime confined here) ========
        if (g2) {
            f32x4 acc2[2][2] = {};   // zero init; b3 added in epilogue
            const unsigned char* r0 = h2p + (rhalf * 32 + l15) * HSTR + koff;
            const unsigned char* r1 = r0 + 16 * HSTR;
            #pragma unroll
            for (int ks = 0; ks < 2; ++ks) {
                {
                    i32x8 hb = ld32(r0 + ks * 128);
                    __builtin_amdgcn_s_setprio(1);
                    #pragma unroll
                    for (int cb = 0; cb < 2; ++cb)
                        acc2[0][cb] = MFMA_MX(w3f[ks][cb], hb, acc2[0][cb]);
                    __builtin_amdgcn_s_setprio(0);
                }
                {
                    i32x8 hb = ld32(r1 + ks * 128);
                    __builtin_amdgcn_s_setprio(1);
                    #pragma unroll
                    for (int cb = 0; cb < 2; ++cb)
                        acc2[1][cb] = MFMA_MX(w3f[ks][cb], hb, acc2[1][cb]);
                    __builtin_amdgcn_s_setprio(0);
                }
            }

            // epilogue2: b3/w4 loaded here (short live ranges, L1-hot)
            #pragma unroll
            for (int rb = 0; rb < 2; ++rb) {
                float pp = 0.f;
                #pragma unroll
                for (int cb = 0; cb < 2; ++cb) {
                    f32x4 b3v = *reinterpret_cast<const f32x4*>(&sf_b3[cgrp * 32 + cb * 16 + l4 * 4]);
                    f32x4 w4v = *reinterpret_cast<const f32x4*>(&sf_w4[cgrp * 32 + cb * 16 + l4 * 4]);
                    #pragma unroll
                    for (int i = 0; i < 4; ++i) {
                        float v = fmaxf(acc2[rb][cb][i] + b3v[i], 0.f);
                        pp = fmaf(v, w4v[i], pp);
                    }
                }
                partials[tg2 & 3][rhalf * 32 + rb * 16 + l15][cgrp * 4 + l4] = pp;
            }
        }

        // build h1 for tile t+2 (read in the NEXT pair, after the barrier)
        if (t + 2 < 64) build(t + 2);

        // final store for tile t-4 (partials written one pair ago)
        const int tf = t - 4;
        if (tf >= 0 && tid < 64) {
            const f32x4* pr = reinterpret_cast<const f32x4*>(&partials[tf & 3][tid][0]);
            f32x4 ss = pr[0] + pr[1] + pr[2] + pr[3];
            float s = ss[0] + ss[1] + ss[2] + ss[3] + b4v;
            out[b * GG + tf * 64 + tid] = 1.f / (1.f + __expf(-s));
        }
    };

    // prologue: tiles 0 and 1
    build(0);
    build(1);
    __syncthreads();

    #pragma unroll 1
    for (int t0 = 0; t0 < 68; t0 += 2) {
        subphase(t0);
        subphase(t0 + 1);
        __syncthreads();
    }
}

// ---------------------------------------------------------------------------
extern "C" void kernel_launch(void* const* d_in, const int* in_sizes, int n_in,
                              void* d_out, int out_size, void* d_ws, size_t ws_size,
                              hipStream_t stream)
{
    const float* features = (const float*)d_in[0];
    const float* coords   = (const float*)d_in[1];
    const float* ce_w1 = (const float*)d_in[2];
    const float* ce_b1 = (const float*)d_in[3];
    const float* ce_w2 = (const float*)d_in[4];
    const float* ce_b2 = (const float*)d_in[5];
    const float* ce_w3 = (const float*)d_in[6];
    const float* ce_b3 = (const float*)d_in[7];
    const float* sf_w1 = (const float*)d_in[8];
    const float* sf_b1 = (const float*)d_in[9];
    const float* sf_w2 = (const float*)d_in[10];
    const float* sf_b2 = (const float*)d_in[11];
    const float* sf_w3 = (const float*)d_in[12];
    const float* sf_b3 = (const float*)d_in[13];
    const float* sf_w4 = (const float*)d_in[14];
    const float* sf_b4 = (const float*)d_in[15];
    float* out = (float*)d_out;

    char* ws = (char*)d_ws;
    float*        zpart = (float*)ws;                             // 256 KB
    unsigned int* w2t8  = (unsigned int*)(ws + 262144);           //  64 KB
    unsigned int* w3t8  = (unsigned int*)(ws + 262144 + 65536);   //  32 KB
    float*        w1t   = (float*)(ws + 262144 + 65536 + 32768);  //   1 MB (optional)
    const size_t need_w1t = (size_t)(262144 + 65536 + 32768) + (size_t)FD * HD * 4;
    float* w1t_ptr = (ws_size >= need_w1t) ? w1t : nullptr;

    hipLaunchKernelGGL(prep_kernel, dim3(1024), dim3(256), 0, stream,
                       ce_w1, sf_w2, sf_w3, w1t_ptr, w2t8, w3t8);
    hipLaunchKernelGGL(ce_kernel, dim3(256), dim3(256), 0, stream,
                       features, ce_w1, w1t_ptr, ce_b1, ce_w2, ce_b2, ce_w3, ce_b3,
                       sf_w1, sf_b1, zpart);
    hipLaunchKernelGGL(field_kernel, dim3(256), dim3(512), 0, stream,
                       coords, sf_w1, zpart,
                       (const unsigned char*)w2t8, sf_b2,
                       (const unsigned char*)w3t8, sf_b3, sf_w4, sf_b4, out);
}

// Round 20
// 163.033 us; speedup vs baseline: 3.6499x; 1.0147x over previous
//
#include <hip/hip_runtime.h>
#include <hip/hip_bf16.h>

typedef __bf16 bf16_t;
typedef __attribute__((ext_vector_type(4))) float f32x4;
typedef __attribute__((ext_vector_type(8))) int i32x8;

#define FD 1024
#define HD 256
#define GG 4096
#define HSTR 272   // padded LDS row stride (bytes); b128 reads at structural floor

// pack 4 f32 -> 4 OCP e4m3 bytes (v_cvt_pk_fp8_f32, gfx950 = OCP)
__device__ inline unsigned int pack4_fp8(float a, float b, float c, float d) {
    int v = __builtin_amdgcn_cvt_pk_fp8_f32(a, b, 0, false);
    v = __builtin_amdgcn_cvt_pk_fp8_f32(c, d, v, true);
    return (unsigned int)v;
}

// MX-scaled MFMA, fp8(e4m3) A/B, K=128, UNIT scales (exact; verified r14/r15)
#define MFMA_MX(A, B, C) \
    __builtin_amdgcn_mfma_scale_f32_16x16x128_f8f6f4((A), (B), (C), 0, 0, 0, 127, 0, 127)

// ---------------------------------------------------------------------------
// prep: w1t = ce_w1^T (fp32, coalesced CE dot); w2t8/w3t8 = fp8 N-major
// ---------------------------------------------------------------------------
__global__ __launch_bounds__(256) void prep_kernel(
    const float* __restrict__ ce_w1,   // [1024,256]
    const float* __restrict__ sf_w2,   // [256,256]
    const float* __restrict__ sf_w3,   // [256,128]
    float* __restrict__ w1t,           // [256,1024]  (may be null)
    unsigned int* __restrict__ w2t8,   // [256 n][256 k] fp8, as u32[16384]
    unsigned int* __restrict__ w3t8)   // [128 n][256 k] fp8, as u32[8192]
{
    int id = blockIdx.x * 256 + threadIdx.x;   // 0..262143
    if (w1t != nullptr) {
        int j = id >> 10, k = id & 1023;
        w1t[id] = ce_w1[k * 256 + j];
    }
    if (id < 16384) {
        int n = id >> 6, k4 = (id & 63) << 2;
        w2t8[id] = pack4_fp8(sf_w2[(k4 + 0) * 256 + n], sf_w2[(k4 + 1) * 256 + n],
                             sf_w2[(k4 + 2) * 256 + n], sf_w2[(k4 + 3) * 256 + n]);
    }
    if (id < 8192) {
        int n = id >> 6, k4 = (id & 63) << 2;
        w3t8[id] = pack4_fp8(sf_w3[(k4 + 0) * 128 + n], sf_w3[(k4 + 1) * 128 + n],
                             sf_w3[(k4 + 2) * 128 + n], sf_w3[(k4 + 3) * 128 + n]);
    }
}

// ---------------------------------------------------------------------------
// context encoder: one block per batch row; fp32 throughout.
// ---------------------------------------------------------------------------
__global__ __launch_bounds__(256) void ce_kernel(
    const float* __restrict__ features,
    const float* __restrict__ ce_w1,
    const float* __restrict__ w1t,
    const float* __restrict__ ce_b1,
    const float* __restrict__ ce_w2, const float* __restrict__ ce_b2,
    const float* __restrict__ ce_w3, const float* __restrict__ ce_b3,
    const float* __restrict__ sf_w1,
    const float* __restrict__ sf_b1,
    float* __restrict__ zpart)
{
    __shared__ float fs[FD];
    __shared__ float z1[HD];
    __shared__ float z2[HD / 2];
    __shared__ float zc[64];
    const int b = blockIdx.x, t = threadIdx.x;

    #pragma unroll
    for (int i = 0; i < 4; ++i) fs[t + i * 256] = features[b * FD + t + i * 256];
    __syncthreads();

    {
        float s = ce_b1[t];
        if (w1t != nullptr) {
            const float4* wr = reinterpret_cast<const float4*>(w1t + t * FD);
            #pragma unroll 4
            for (int k = 0; k < FD / 4; ++k) {
                float4 w = wr[k];
                const float4 f = *reinterpret_cast<const float4*>(&fs[k * 4]);
                s = fmaf(w.x, f.x, s);
                s = fmaf(w.y, f.y, s);
                s = fmaf(w.z, f.z, s);
                s = fmaf(w.w, f.w, s);
            }
        } else {
            #pragma unroll 8
            for (int k = 0; k < FD; ++k) s = fmaf(fs[k], ce_w1[k * 256 + t], s);
        }
        z1[t] = s > 0.f ? s : 0.f;
    }
    __syncthreads();

    if (t < 128) {
        float s = ce_b2[t];
        #pragma unroll 8
        for (int k = 0; k < 256; ++k) s = fmaf(z1[k], ce_w2[k * 128 + t], s);
        z2[t] = s > 0.f ? s : 0.f;
    }
    __syncthreads();

    if (t < 64) {
        float s = ce_b3[t];
        #pragma unroll 8
        for (int k = 0; k < 128; ++k) s = fmaf(z2[k], ce_w3[k * 64 + t], s);
        zc[t] = s;
    }
    __syncthreads();

    {
        float s = sf_b1[t];
        #pragma unroll 8
        for (int k = 0; k < 64; ++k) s = fmaf(zc[k], sf_w1[(2 + k) * 256 + t], s);
        zpart[b * HD + t] = s;
    }
}

// ---------------------------------------------------------------------------
// fused field MLP, fp8 MX K=128, WAVE-SPECIALIZED producer/consumer:
//   waves 0-3 (role A): GEMM1(t) 64rx64c each (32 MFMA) + epi1 + store(t-4)
//   waves 4-7 (role B): GEMM2(t-2) 32rx64c each (16 MFMA) + epi2 + build(t+2)
//   SIMD s hosts waves s (A) and s+4 (B) -> A's MFMA cluster overlaps B's
//   VALU (build/epi) per m114 co-schedule; no occupancy needed.
//   4-deep h1/h2/partials, 1 barrier/2 tiles; all cross-role RAW spans the
//   pair barrier (indices mod 4 disjoint within a pair -- r15 discipline).
//   Weight frags UNIONED in wf[2][4] (A: w2 slice, B: w3 slice).
//   grid=256 (1 block/CU), 512 thr.
// ---------------------------------------------------------------------------
__global__ __launch_bounds__(512, 2) void field_kernel(
    const float* __restrict__ coords,   // [4096,2]
    const float* __restrict__ sf_w1,    // [66,256] rows 0,1 used
    const float* __restrict__ zpart,    // [256,256]
    const unsigned char* __restrict__ w2t8, // [256 n][256 k] fp8
    const float* __restrict__ sf_b2,    // [256]
    const unsigned char* __restrict__ w3t8, // [128 n][256 k] fp8
    const float* __restrict__ sf_b3,    // [128]
    const float* __restrict__ sf_w4,    // [128]
    const float* __restrict__ sf_b4,    // [1]
    float* __restrict__ out)            // [256,4096]
{
    __shared__ __attribute__((aligned(128))) unsigned char h1[4][64 * HSTR];  // 68 KB
    __shared__ __attribute__((aligned(128))) unsigned char h2[4][64 * HSTR];  // 68 KB
    __shared__ float partials[4][64][12];                                     // 12 KB

    const int b = blockIdx.x;
    const int tid = threadIdx.x;
    const int wid = tid >> 6;
    const int lane = tid & 63;
    const int l15 = lane & 15;
    const int l4 = lane >> 4;
    const int koff = l4 * 32;          // lane's 32B k-slice within a 128-k step
    const bool roleA = (wid < 4);

    // ---- unioned resident weight fragments ----
    // role A: w2^T cols wid*64 .. +63 ; role B: w3^T cols (w'>>1)*64 .. +63
    i32x8 wf[2][4];
    if (roleA) {
        const int cg = wid;
        #pragma unroll
        for (int ks = 0; ks < 2; ++ks)
            #pragma unroll
            for (int n = 0; n < 4; ++n)
                wf[ks][n] = *reinterpret_cast<const i32x8*>(
                    &w2t8[(cg * 64 + n * 16 + l15) * 256 + ks * 128 + koff]);
    } else {
        const int ch = (wid - 4) >> 1;
        #pragma unroll
        for (int ks = 0; ks < 2; ++ks)
            #pragma unroll
            for (int cb = 0; cb < 4; ++cb)
                wf[ks][cb] = *reinterpret_cast<const i32x8*>(
                    &w3t8[(ch * 64 + cb * 16 + l15) * 256 + ks * 128 + koff]);
    }

    // ---- role A residents: b2 slice (C-init) ----
    f32x4 b2r[4];
    if (roleA) {
        #pragma unroll
        for (int n = 0; n < 4; ++n)
            b2r[n] = *reinterpret_cast<const f32x4*>(&sf_b2[wid * 64 + n * 16 + l4 * 4]);
    }
    const float b4v = sf_b4[0];

    // ---- role B residents: h1-build constants (8 rows/thread) ----
    const int tl = tid & 255;
    const int kc = tl & 31;            // 8B chunk within row
    const int rbase = tl >> 5;         // 0..7 ; rows rbase + it*8
    float zpf[8], waf[8], wbf[8], xvr[8];
    if (!roleA) {
        #pragma unroll
        for (int j = 0; j < 8; ++j) {
            zpf[j] = zpart[b * HD + kc * 8 + j];
            waf[j] = sf_w1[kc * 8 + j];
            wbf[j] = sf_w1[HD + kc * 8 + j];
        }
        #pragma unroll
        for (int it = 0; it < 8; ++it)
            xvr[it] = coords[2 * (it * 8 + rbase) + 1];   // yy, tile-invariant
    }

    // contiguous 32B LDS operand: 2 x 16B (2 ds_read_b128)
    auto ld32 = [&](const unsigned char* p) -> i32x8 {
        uint4 a = *reinterpret_cast<const uint4*>(p);
        uint4 c = *reinterpret_cast<const uint4*>(p + 16);
        i32x8 r;
        r[0] = a.x; r[1] = a.y; r[2] = a.z; r[3] = a.w;
        r[4] = c.x; r[5] = c.y; r[6] = c.z; r[7] = c.w;
        return r;
    };

    auto build = [&](int t) {          // role B only
        unsigned char* buf = h1[t & 3];
        float x0 = coords[t * 128];    // xx tile-constant
        float zc8[8];
        #pragma unroll
        for (int j = 0; j < 8; ++j) zc8[j] = fmaf(x0, waf[j], zpf[j]);
        #pragma unroll
        for (int it = 0; it < 8; ++it) {
            float xv = xvr[it];
            float s[8];
            #pragma unroll
            for (int j = 0; j < 8; ++j) {
                float v = fmaf(xv, wbf[j], zc8[j]);
                s[j] = v > 0.f ? v : 0.f;
            }
            uint2 pk;
            pk.x = pack4_fp8(s[0], s[1], s[2], s[3]);
            pk.y = pack4_fp8(s[4], s[5], s[6], s[7]);
            *reinterpret_cast<uint2*>(&buf[(it * 8 + rbase) * HSTR + kc * 8]) = pk;
        }
    };

    // ---- role A sub-phase: GEMM1(t) + epi1 + store(t-4) ----
    auto subA = [&](int t) {
        if (t < 64) {
            const unsigned char* h1c = h1[t & 3];
            f32x4 acc1[4][4];
            #pragma unroll
            for (int m = 0; m < 4; ++m)
                #pragma unroll
                for (int n = 0; n < 4; ++n) acc1[m][n] = b2r[n];   // bias C-init

            #pragma unroll
            for (int m = 0; m < 4; ++m) {
                const unsigned char* rp = h1c + (m * 16 + l15) * HSTR + koff;
                #pragma unroll
                for (int ks = 0; ks < 2; ++ks) {
                    i32x8 a = ld32(rp + ks * 128);
                    __builtin_amdgcn_s_setprio(1);
                    #pragma unroll
                    for (int n = 0; n < 4; ++n)
                        acc1[m][n] = MFMA_MX(wf[ks][n], a, acc1[m][n]);
                    __builtin_amdgcn_s_setprio(0);
                }
            }

            // epi1: h2 = relu(acc1) -> h2[t&3]
            unsigned char* h2c = h2[t & 3];
            #pragma unroll
            for (int n = 0; n < 4; ++n) {
                #pragma unroll
                for (int m = 0; m < 4; ++m) {
                    int row = m * 16 + l15;
                    int col = wid * 64 + n * 16 + l4 * 4;
                    float x0 = fmaxf(acc1[m][n][0], 0.f);
                    float x1 = fmaxf(acc1[m][n][1], 0.f);
                    float x2 = fmaxf(acc1[m][n][2], 0.f);
                    float x3 = fmaxf(acc1[m][n][3], 0.f);
                    *reinterpret_cast<unsigned int*>(&h2c[row * HSTR + col]) =
                        pack4_fp8(x0, x1, x2, x3);
                }
            }
        }
        // store tile t-4 (wave 0)
        const int tf = t - 4;
        if (tf >= 0 && wid == 0) {
            const f32x4* pr = reinterpret_cast<const f32x4*>(&partials[tf & 3][lane][0]);
            f32x4 ss = pr[0] + pr[1];
            float s = ss[0] + ss[1] + ss[2] + ss[3] + b4v;
            out[b * GG + tf * 64 + lane] = 1.f / (1.f + __expf(-s));
        }
    };

    // ---- role B sub-phase: GEMM2(t-2) + epi2 + build(t+2) ----
    auto subB = [&](int t) {
        const int tg2 = t - 2;
        const int wp = wid - 4;
        const int rh = wp & 1;         // h2 row half (32 rows)
        const int ch = wp >> 1;        // w3 col half (64 cols)
        if (tg2 >= 0 && tg2 < 64) {
            const unsigned char* h2p = h2[tg2 & 3];
            f32x4 acc2[2][4] = {};     // zero init; b3 added in epilogue
            #pragma unroll
            for (int rb = 0; rb < 2; ++rb) {
                const unsigned char* rp = h2p + (rh * 32 + rb * 16 + l15) * HSTR + koff;
                #pragma unroll
                for (int ks = 0; ks < 2; ++ks) {
                    i32x8 hb = ld32(rp + ks * 128);
                    __builtin_amdgcn_s_setprio(1);
                    #pragma unroll
                    for (int cb = 0; cb < 4; ++cb)
                        acc2[rb][cb] = MFMA_MX(wf[ks][cb], hb, acc2[rb][cb]);
                    __builtin_amdgcn_s_setprio(0);
                }
            }
            // epi2: relu + w4 dot -> partials[tg2&3]
            #pragma unroll
            for (int rb = 0; rb < 2; ++rb) {
                float pp = 0.f;
                #pragma unroll
                for (int cb = 0; cb < 4; ++cb) {
                    f32x4 b3v = *reinterpret_cast<const f32x4*>(&sf_b3[ch * 64 + cb * 16 + l4 * 4]);
                    f32x4 w4v = *reinterpret_cast<const f32x4*>(&sf_w4[ch * 64 + cb * 16 + l4 * 4]);
                    #pragma unroll
                    for (int i = 0; i < 4; ++i) {
                        float v = fmaxf(acc2[rb][cb][i] + b3v[i], 0.f);
                        pp = fmaf(v, w4v[i], pp);
                    }
                }
                partials[tg2 & 3][rh * 32 + rb * 16 + l15][ch * 4 + l4] = pp;
            }
        }
        // build h1 for tile t+2 (read in the NEXT pair, after the barrier)
        if (t + 2 < 64) build(t + 2);
    };

    // prologue: role B builds tiles 0 and 1
    if (!roleA) { build(0); build(1); }
    __syncthreads();

    #pragma unroll 1
    for (int t0 = 0; t0 < 68; t0 += 2) {
        if (roleA) { subA(t0); subA(t0 + 1); }
        else       { subB(t0); subB(t0 + 1); }
        __syncthreads();
    }
}

// ---------------------------------------------------------------------------
extern "C" void kernel_launch(void* const* d_in, const int* in_sizes, int n_in,
                              void* d_out, int out_size, void* d_ws, size_t ws_size,
                              hipStream_t stream)
{
    const float* features = (const float*)d_in[0];
    const float* coords   = (const float*)d_in[1];
    const float* ce_w1 = (const float*)d_in[2];
    const float* ce_b1 = (const float*)d_in[3];
    const float* ce_w2 = (const float*)d_in[4];
    const float* ce_b2 = (const float*)d_in[5];
    const float* ce_w3 = (const float*)d_in[6];
    const float* ce_b3 = (const float*)d_in[7];
    const float* sf_w1 = (const float*)d_in[8];
    const float* sf_b1 = (const float*)d_in[9];
    const float* sf_w2 = (const float*)d_in[10];
    const float* sf_b2 = (const float*)d_in[11];
    const float* sf_w3 = (const float*)d_in[12];
    const float* sf_b3 = (const float*)d_in[13];
    const float* sf_w4 = (const float*)d_in[14];
    const float* sf_b4 = (const float*)d_in[15];
    float* out = (float*)d_out;

    char* ws = (char*)d_ws;
    float*        zpart = (float*)ws;                             // 256 KB
    unsigned int* w2t8  = (unsigned int*)(ws + 262144);           //  64 KB
    unsigned int* w3t8  = (unsigned int*)(ws + 262144 + 65536);   //  32 KB
    float*        w1t   = (float*)(ws + 262144 + 65536 + 32768);  //   1 MB (optional)
    const size_t need_w1t = (size_t)(262144 + 65536 + 32768) + (size_t)FD * HD * 4;
    float* w1t_ptr = (ws_size >= need_w1t) ? w1t : nullptr;

    hipLaunchKernelGGL(prep_kernel, dim3(1024), dim3(256), 0, stream,
                       ce_w1, sf_w2, sf_w3, w1t_ptr, w2t8, w3t8);
    hipLaunchKernelGGL(ce_kernel, dim3(256), dim3(256), 0, stream,
                       features, ce_w1, w1t_ptr, ce_b1, ce_w2, ce_b2, ce_w3, ce_b3,
                       sf_w1, sf_b1, zpart);
    hipLaunchKernelGGL(field_kernel, dim3(256), dim3(512), 0, stream,
                       coords, sf_w1, zpart,
                       (const unsigned char*)w2t8, sf_b2,
                       (const unsigned char*)w3t8, sf_b3, sf_w4, sf_b4, out);
}

// Round 21
// 159.874 us; speedup vs baseline: 3.7221x; 1.0198x over previous
//
#include <hip/hip_runtime.h>
#include <hip/hip_bf16.h>

typedef __bf16 bf16_t;
typedef __attribute__((ext_vector_type(4))) float f32x4;
typedef __attribute__((ext_vector_type(8))) int i32x8;

#define FD 1024
#define HD 256
#define GG 4096
#define HSTR 272   // padded LDS row stride (bytes)

// pack 4 f32 -> 4 OCP e4m3 bytes (v_cvt_pk_fp8_f32, gfx950 = OCP)
__device__ inline unsigned int pack4_fp8(float a, float b, float c, float d) {
    int v = __builtin_amdgcn_cvt_pk_fp8_f32(a, b, 0, false);
    v = __builtin_amdgcn_cvt_pk_fp8_f32(c, d, v, true);
    return (unsigned int)v;
}

// MX-scaled MFMA, fp8(e4m3) A/B, K=128, UNIT scales (exact; verified r14/r15)
#define MFMA_MX(A, B, C) \
    __builtin_amdgcn_mfma_scale_f32_16x16x128_f8f6f4((A), (B), (C), 0, 0, 0, 127, 0, 127)

// ---------------------------------------------------------------------------
// prep: w1t = ce_w1^T (fp32, coalesced CE dot); w2t8/w3t8 = fp8 N-major
// ---------------------------------------------------------------------------
__global__ __launch_bounds__(256) void prep_kernel(
    const float* __restrict__ ce_w1,   // [1024,256]
    const float* __restrict__ sf_w2,   // [256,256]
    const float* __restrict__ sf_w3,   // [256,128]
    float* __restrict__ w1t,           // [256,1024]  (may be null)
    unsigned int* __restrict__ w2t8,   // [256 n][256 k] fp8, as u32[16384]
    unsigned int* __restrict__ w3t8)   // [128 n][256 k] fp8, as u32[8192]
{
    int id = blockIdx.x * 256 + threadIdx.x;   // 0..262143
    if (w1t != nullptr) {
        int j = id >> 10, k = id & 1023;
        w1t[id] = ce_w1[k * 256 + j];
    }
    if (id < 16384) {
        int n = id >> 6, k4 = (id & 63) << 2;
        w2t8[id] = pack4_fp8(sf_w2[(k4 + 0) * 256 + n], sf_w2[(k4 + 1) * 256 + n],
                             sf_w2[(k4 + 2) * 256 + n], sf_w2[(k4 + 3) * 256 + n]);
    }
    if (id < 8192) {
        int n = id >> 6, k4 = (id & 63) << 2;
        w3t8[id] = pack4_fp8(sf_w3[(k4 + 0) * 128 + n], sf_w3[(k4 + 1) * 128 + n],
                             sf_w3[(k4 + 2) * 128 + n], sf_w3[(k4 + 3) * 128 + n]);
    }
}

// ---------------------------------------------------------------------------
// context encoder: one block per batch row; fp32 throughout.
// zpart[b][j] = z_c[b] @ sf_w1[2:] + sf_b1   (bias folded in)
// ---------------------------------------------------------------------------
__global__ __launch_bounds__(256) void ce_kernel(
    const float* __restrict__ features,
    const float* __restrict__ ce_w1,
    const float* __restrict__ w1t,
    const float* __restrict__ ce_b1,
    const float* __restrict__ ce_w2, const float* __restrict__ ce_b2,
    const float* __restrict__ ce_w3, const float* __restrict__ ce_b3,
    const float* __restrict__ sf_w1,
    const float* __restrict__ sf_b1,
    float* __restrict__ zpart)
{
    __shared__ float fs[FD];
    __shared__ float z1[HD];
    __shared__ float z2[HD / 2];
    __shared__ float zc[64];
    const int b = blockIdx.x, t = threadIdx.x;

    #pragma unroll
    for (int i = 0; i < 4; ++i) fs[t + i * 256] = features[b * FD + t + i * 256];
    __syncthreads();

    {
        float s = ce_b1[t];
        if (w1t != nullptr) {
            const float4* wr = reinterpret_cast<const float4*>(w1t + t * FD);
            #pragma unroll 4
            for (int k = 0; k < FD / 4; ++k) {
                float4 w = wr[k];
                const float4 f = *reinterpret_cast<const float4*>(&fs[k * 4]);
                s = fmaf(w.x, f.x, s);
                s = fmaf(w.y, f.y, s);
                s = fmaf(w.z, f.z, s);
                s = fmaf(w.w, f.w, s);
            }
        } else {
            #pragma unroll 8
            for (int k = 0; k < FD; ++k) s = fmaf(fs[k], ce_w1[k * 256 + t], s);
        }
        z1[t] = s > 0.f ? s : 0.f;
    }
    __syncthreads();

    if (t < 128) {
        float s = ce_b2[t];
        #pragma unroll 8
        for (int k = 0; k < 256; ++k) s = fmaf(z1[k], ce_w2[k * 128 + t], s);
        z2[t] = s > 0.f ? s : 0.f;
    }
    __syncthreads();

    if (t < 64) {
        float s = ce_b3[t];
        #pragma unroll 8
        for (int k = 0; k < 128; ++k) s = fmaf(z2[k], ce_w3[k * 64 + t], s);
        zc[t] = s;
    }
    __syncthreads();

    {
        float s = sf_b1[t];
        #pragma unroll 8
        for (int k = 0; k < 64; ++k) s = fmaf(zc[k], sf_w1[(2 + k) * 256 + t], s);
        zpart[b * HD + t] = s;
    }
}

// ---------------------------------------------------------------------------
// fused field MLP, fp8 MX K=128 (unit scales), weight-stationary, 4-deep
// pipeline, 1 barrier/2 tiles, padded-linear LDS (r19 structure) with
// COMPILE-TIME BUFFER INDICES: main loop unrolled by 4, subphase takes the
// literal phase parity tm = t mod 4, so all h1/h2/partials bases are
// constants -> LDS addresses are loop-invariant / folded into ds offsets
// (cuts the addressing VALU that dominated r19's 52% VALUBusy).
//   grid=256 (1 block/CU), 512 thr (8 waves, 2/SIMD -- unified-VGPR cap).
//   Sub-phase t: GEMM1(t)+epi1 ; GEMM2(t-2)+epi2 ; build h1(t+2) ; store(t-4)
//   Register discipline from r15; b3/w4 now RESIDENT (occupancy is pinned
//   at 2 waves/SIMD anyway, so the +16 VGPR are free).
// ---------------------------------------------------------------------------
__global__ __launch_bounds__(512, 2) void field_kernel(
    const float* __restrict__ coords,   // [4096,2]
    const float* __restrict__ sf_w1,    // [66,256] rows 0,1 used
    const float* __restrict__ zpart,    // [256,256]
    const unsigned char* __restrict__ w2t8, // [256 n][256 k] fp8
    const float* __restrict__ sf_b2,    // [256]
    const unsigned char* __restrict__ w3t8, // [128 n][256 k] fp8
    const float* __restrict__ sf_b3,    // [128]
    const float* __restrict__ sf_w4,    // [128]
    const float* __restrict__ sf_b4,    // [1]
    float* __restrict__ out)            // [256,4096]
{
    __shared__ __attribute__((aligned(128))) unsigned char h1[4][64 * HSTR];  // 68 KB
    __shared__ __attribute__((aligned(128))) unsigned char h2[4][64 * HSTR];  // 68 KB
    __shared__ float partials[4][64][20];                                     // 20 KB

    const int b = blockIdx.x;
    const int tid = threadIdx.x;
    const int wid = tid >> 6;
    const int lane = tid & 63;
    const int l15 = lane & 15;
    const int l4 = lane >> 4;
    const int koff = l4 * 32;          // lane's 32B k-slice within a 128-k step

    // ---- resident weights (MX K=128 fragments: lane k = ks*128 + l4*32 + 0..31) ----
    const int cg1 = wid & 3;    // GEMM1 col group (64 cols)
    const int rg1 = wid >> 2;   // GEMM1 row group (32 rows)
    i32x8 b1f[2][4];
    #pragma unroll
    for (int ks = 0; ks < 2; ++ks)
        #pragma unroll
        for (int n = 0; n < 4; ++n)
            b1f[ks][n] = *reinterpret_cast<const i32x8*>(
                &w2t8[(cg1 * 64 + n * 16 + l15) * 256 + ks * 128 + koff]);

    const int cgrp = wid & 3, rhalf = wid >> 2;
    i32x8 w3f[2][2];
    #pragma unroll
    for (int ks = 0; ks < 2; ++ks)
        #pragma unroll
        for (int cb = 0; cb < 2; ++cb)
            w3f[ks][cb] = *reinterpret_cast<const i32x8*>(
                &w3t8[(cgrp * 32 + cb * 16 + l15) * 256 + ks * 128 + koff]);

    // ---- resident bias / w4 vectors ----
    f32x4 b2r[4];
    #pragma unroll
    for (int n = 0; n < 4; ++n)
        b2r[n] = *reinterpret_cast<const f32x4*>(&sf_b2[cg1 * 64 + n * 16 + l4 * 4]);
    f32x4 b3r[2], w4r[2];
    #pragma unroll
    for (int cb = 0; cb < 2; ++cb) {
        b3r[cb] = *reinterpret_cast<const f32x4*>(&sf_b3[cgrp * 32 + cb * 16 + l4 * 4]);
        w4r[cb] = *reinterpret_cast<const f32x4*>(&sf_w4[cgrp * 32 + cb * 16 + l4 * 4]);
    }
    const float b4v = sf_b4[0];

    // ---- h1-build constants (meshgrid: xx tile-const, yy thread-invariant) ----
    const int kc = tid & 31;           // 8B chunk within row (linear)
    const int rbase = tid >> 5;        // row base 0..15 (rows rbase+16*it)
    float zpf[8], waf[8], wbf[8];
    #pragma unroll
    for (int j = 0; j < 8; ++j) {
        zpf[j] = zpart[b * HD + kc * 8 + j];
        waf[j] = sf_w1[kc * 8 + j];
        wbf[j] = sf_w1[HD + kc * 8 + j];
    }
    float xvr[4];
    #pragma unroll
    for (int it = 0; it < 4; ++it)
        xvr[it] = coords[2 * (it * 16 + rbase) + 1];   // yy = x[row], tile-invariant

    // contiguous 32B LDS operand: 2 x 16B (2 ds_read_b128)
    auto ld32 = [&](const unsigned char* p) -> i32x8 {
        uint4 a = *reinterpret_cast<const uint4*>(p);
        uint4 c = *reinterpret_cast<const uint4*>(p + 16);
        i32x8 r;
        r[0] = a.x; r[1] = a.y; r[2] = a.z; r[3] = a.w;
        r[4] = c.x; r[5] = c.y; r[6] = c.z; r[7] = c.w;
        return r;
    };

    // build tile t into buffer bi (bi literal at call sites)
    auto build = [&](int t, int bi) {
        unsigned char* buf = h1[bi];
        float x0 = coords[t * 128];    // xx tile-constant
        float zc8[8];
        #pragma unroll
        for (int j = 0; j < 8; ++j) zc8[j] = fmaf(x0, waf[j], zpf[j]);
        #pragma unroll
        for (int it = 0; it < 4; ++it) {
            float xv = xvr[it];
            float s[8];
            #pragma unroll
            for (int j = 0; j < 8; ++j) {
                float v = fmaf(xv, wbf[j], zc8[j]);
                s[j] = v > 0.f ? v : 0.f;
            }
            uint2 pk;
            pk.x = pack4_fp8(s[0], s[1], s[2], s[3]);
            pk.y = pack4_fp8(s[4], s[5], s[6], s[7]);
            *reinterpret_cast<uint2*>(&buf[(it * 16 + rbase) * HSTR + kc * 8]) = pk;
        }
    };

    // subphase with LITERAL tm = t mod 4 (all buffer indices compile-time)
    auto subphase = [&](int t, int tm) {
        const int tg2 = t - 2;
        const bool g1 = (t < 64);
        const bool g2 = (tg2 >= 0) && (tg2 < 64);
        const unsigned char* h1c = h1[tm];
        const unsigned char* h2p = h2[(tm + 2) & 3];   // (t-2) mod 4

        // ======== GEMM1(t) + epilogue1 (acc1 lifetime confined here) ========
        if (g1) {
            f32x4 acc1[2][4];
            #pragma unroll
            for (int m = 0; m < 2; ++m)
                #pragma unroll
                for (int n = 0; n < 4; ++n) acc1[m][n] = b2r[n];   // bias C-init

            const unsigned char* r0 = h1c + (rg1 * 32 + l15) * HSTR + koff;
            const unsigned char* r1 = r0 + 16 * HSTR;
            #pragma unroll
            for (int ks = 0; ks < 2; ++ks) {
                {
                    i32x8 a = ld32(r0 + ks * 128);
                    __builtin_amdgcn_s_setprio(1);
                    #pragma unroll
                    for (int n = 0; n < 4; ++n)
                        acc1[0][n] = MFMA_MX(b1f[ks][n], a, acc1[0][n]);
                    __builtin_amdgcn_s_setprio(0);
                }
                {
                    i32x8 a = ld32(r1 + ks * 128);
                    __builtin_amdgcn_s_setprio(1);
                    #pragma unroll
                    for (int n = 0; n < 4; ++n)
                        acc1[1][n] = MFMA_MX(b1f[ks][n], a, acc1[1][n]);
                    __builtin_amdgcn_s_setprio(0);
                }
            }

            // epilogue1: h2 = relu(acc1) (bias pre-added) -> h2[tm]
            unsigned char* h2c = h2[tm];
            #pragma unroll
            for (int n = 0; n < 4; ++n) {
                #pragma unroll
                for (int m = 0; m < 2; ++m) {
                    int row = rg1 * 32 + m * 16 + l15;
                    int col = cg1 * 64 + n * 16 + l4 * 4;
                    float x0 = fmaxf(acc1[m][n][0], 0.f);
                    float x1 = fmaxf(acc1[m][n][1], 0.f);
                    float x2 = fmaxf(acc1[m][n][2], 0.f);
                    float x3 = fmaxf(acc1[m][n][3], 0.f);
                    *reinterpret_cast<unsigned int*>(&h2c[row * HSTR + col]) =
                        pack4_fp8(x0, x1, x2, x3);
                }
            }
        }

        // ======== GEMM2(t-2) + epilogue2 (acc2 lifetime confined here) ========
        if (g2) {
            f32x4 acc2[2][2] = {};   // zero init; b3 added in epilogue
            const unsigned char* r0 = h2p + (rhalf * 32 + l15) * HSTR + koff;
            const unsigned char* r1 = r0 + 16 * HSTR;
            #pragma unroll
            for (int ks = 0; ks < 2; ++ks) {
                {
                    i32x8 hb = ld32(r0 + ks * 128);
                    __builtin_amdgcn_s_setprio(1);
                    #pragma unroll
                    for (int cb = 0; cb < 2; ++cb)
                        acc2[0][cb] = MFMA_MX(w3f[ks][cb], hb, acc2[0][cb]);
                    __builtin_amdgcn_s_setprio(0);
                }
                {
                    i32x8 hb = ld32(r1 + ks * 128);
                    __builtin_amdgcn_s_setprio(1);
                    #pragma unroll
                    for (int cb = 0; cb < 2; ++cb)
                        acc2[1][cb] = MFMA_MX(w3f[ks][cb], hb, acc2[1][cb]);
                    __builtin_amdgcn_s_setprio(0);
                }
            }

            // epilogue2: relu (resident b3) + w4 dot -> partials[(tm+2)&3]
            #pragma unroll
            for (int rb = 0; rb < 2; ++rb) {
                float pp = 0.f;
                #pragma unroll
                for (int cb = 0; cb < 2; ++cb)
                    #pragma unroll
                    for (int i = 0; i < 4; ++i) {
                        float v = fmaxf(acc2[rb][cb][i] + b3r[cb][i], 0.f);
                        pp = fmaf(v, w4r[cb][i], pp);
                    }
                partials[(tm + 2) & 3][rhalf * 32 + rb * 16 + l15][cgrp * 4 + l4] = pp;
            }
        }

        // build h1 for tile t+2 into h1[(tm+2)&3] (read after the barrier)
        if (t + 2 < 64) build(t + 2, (tm + 2) & 3);

        // final store for tile t-4 (partials[tm], written one pair ago)
        const int tf = t - 4;
        if (tf >= 0 && tid < 64) {
            const f32x4* pr = reinterpret_cast<const f32x4*>(&partials[tm][tid][0]);
            f32x4 ss = pr[0] + pr[1] + pr[2] + pr[3];
            float s = ss[0] + ss[1] + ss[2] + ss[3] + b4v;
            out[b * GG + tf * 64 + tid] = 1.f / (1.f + __expf(-s));
        }
    };

    // prologue: tiles 0 and 1
    build(0, 0);
    build(1, 1);
    __syncthreads();

    #pragma unroll 1
    for (int t0 = 0; t0 < 68; t0 += 4) {
        subphase(t0,     0);
        subphase(t0 + 1, 1);
        __syncthreads();
        subphase(t0 + 2, 2);
        subphase(t0 + 3, 3);
        __syncthreads();
    }
}

// ---------------------------------------------------------------------------
extern "C" void kernel_launch(void* const* d_in, const int* in_sizes, int n_in,
                              void* d_out, int out_size, void* d_ws, size_t ws_size,
                              hipStream_t stream)
{
    const float* features = (const float*)d_in[0];
    const float* coords   = (const float*)d_in[1];
    const float* ce_w1 = (const float*)d_in[2];
    const float* ce_b1 = (const float*)d_in[3];
    const float* ce_w2 = (const float*)d_in[4];
    const float* ce_b2 = (const float*)d_in[5];
    const float* ce_w3 = (const float*)d_in[6];
    const float* ce_b3 = (const float*)d_in[7];
    const float* sf_w1 = (const float*)d_in[8];
    const float* sf_b1 = (const float*)d_in[9];
    const float* sf_w2 = (const float*)d_in[10];
    const float* sf_b2 = (const float*)d_in[11];
    const float* sf_w3 = (const float*)d_in[12];
    const float* sf_b3 = (const float*)d_in[13];
    const float* sf_w4 = (const float*)d_in[14];
    const float* sf_b4 = (const float*)d_in[15];
    float* out = (float*)d_out;

    char* ws = (char*)d_ws;
    float*        zpart = (float*)ws;                             // 256 KB
    unsigned int* w2t8  = (unsigned int*)(ws + 262144);           //  64 KB
    unsigned int* w3t8  = (unsigned int*)(ws + 262144 + 65536);   //  32 KB
    float*        w1t   = (float*)(ws + 262144 + 65536 + 32768);  //   1 MB (optional)
    const size_t need_w1t = (size_t)(262144 + 65536 + 32768) + (size_t)FD * HD * 4;
    float* w1t_ptr = (ws_size >= need_w1t) ? w1t : nullptr;

    hipLaunchKernelGGL(prep_kernel, dim3(1024), dim3(256), 0, stream,
                       ce_w1, sf_w2, sf_w3, w1t_ptr, w2t8, w3t8);
    hipLaunchKernelGGL(ce_kernel, dim3(256), dim3(256), 0, stream,
                       features, ce_w1, w1t_ptr, ce_b1, ce_w2, ce_b2, ce_w3, ce_b3,
                       sf_w1, sf_b1, zpart);
    hipLaunchKernelGGL(field_kernel, dim3(256), dim3(512), 0, stream,
                       coords, sf_w1, zpart,
                       (const unsigned char*)w2t8, sf_b2,
                       (const unsigned char*)w3t8, sf_b3, sf_w4, sf_b4, out);
}

// Round 22
// 156.469 us; speedup vs baseline: 3.8030x; 1.0218x over previous
//
#include <hip/hip_runtime.h>
#include <hip/hip_bf16.h>

typedef __bf16 bf16_t;
typedef __attribute__((ext_vector_type(4))) float f32x4;
typedef __attribute__((ext_vector_type(8))) int i32x8;

#define FD 1024
#define HD 256
#define GG 4096
#define HSTR 272   // padded LDS row stride (bytes)

// pack 4 f32 -> 4 OCP e4m3 bytes (v_cvt_pk_fp8_f32, gfx950 = OCP)
__device__ inline unsigned int pack4_fp8(float a, float b, float c, float d) {
    int v = __builtin_amdgcn_cvt_pk_fp8_f32(a, b, 0, false);
    v = __builtin_amdgcn_cvt_pk_fp8_f32(c, d, v, true);
    return (unsigned int)v;
}

// MX-scaled MFMA, fp8(e4m3) A/B, K=128, UNIT scales (exact; verified r14/r15)
#define MFMA_MX(A, B, C) \
    __builtin_amdgcn_mfma_scale_f32_16x16x128_f8f6f4((A), (B), (C), 0, 0, 0, 127, 0, 127)

// ---------------------------------------------------------------------------
// prep: w1t = ce_w1^T (fp32, coalesced CE dot); w2t8/w3t8 = fp8 N-major
// ---------------------------------------------------------------------------
__global__ __launch_bounds__(256) void prep_kernel(
    const float* __restrict__ ce_w1,   // [1024,256]
    const float* __restrict__ sf_w2,   // [256,256]
    const float* __restrict__ sf_w3,   // [256,128]
    float* __restrict__ w1t,           // [256,1024]  (may be null)
    unsigned int* __restrict__ w2t8,   // [256 n][256 k] fp8, as u32[16384]
    unsigned int* __restrict__ w3t8)   // [128 n][256 k] fp8, as u32[8192]
{
    int id = blockIdx.x * 256 + threadIdx.x;   // 0..262143
    if (w1t != nullptr) {
        int j = id >> 10, k = id & 1023;
        w1t[id] = ce_w1[k * 256 + j];
    }
    if (id < 16384) {
        int n = id >> 6, k4 = (id & 63) << 2;
        w2t8[id] = pack4_fp8(sf_w2[(k4 + 0) * 256 + n], sf_w2[(k4 + 1) * 256 + n],
                             sf_w2[(k4 + 2) * 256 + n], sf_w2[(k4 + 3) * 256 + n]);
    }
    if (id < 8192) {
        int n = id >> 6, k4 = (id & 63) << 2;
        w3t8[id] = pack4_fp8(sf_w3[(k4 + 0) * 128 + n], sf_w3[(k4 + 1) * 128 + n],
                             sf_w3[(k4 + 2) * 128 + n], sf_w3[(k4 + 3) * 128 + n]);
    }
}

// ---------------------------------------------------------------------------
// context encoder: one block per batch row; fp32 throughout.
// zpart[b][j] = z_c[b] @ sf_w1[2:] + sf_b1   (bias folded in)
// ---------------------------------------------------------------------------
__global__ __launch_bounds__(256) void ce_kernel(
    const float* __restrict__ features,
    const float* __restrict__ ce_w1,
    const float* __restrict__ w1t,
    const float* __restrict__ ce_b1,
    const float* __restrict__ ce_w2, const float* __restrict__ ce_b2,
    const float* __restrict__ ce_w3, const float* __restrict__ ce_b3,
    const float* __restrict__ sf_w1,
    const float* __restrict__ sf_b1,
    float* __restrict__ zpart)
{
    __shared__ float fs[FD];
    __shared__ float z1[HD];
    __shared__ float z2[HD / 2];
    __shared__ float zc[64];
    const int b = blockIdx.x, t = threadIdx.x;

    #pragma unroll
    for (int i = 0; i < 4; ++i) fs[t + i * 256] = features[b * FD + t + i * 256];
    __syncthreads();

    {
        float s = ce_b1[t];
        if (w1t != nullptr) {
            const float4* wr = reinterpret_cast<const float4*>(w1t + t * FD);
            #pragma unroll 4
            for (int k = 0; k < FD / 4; ++k) {
                float4 w = wr[k];
                const float4 f = *reinterpret_cast<const float4*>(&fs[k * 4]);
                s = fmaf(w.x, f.x, s);
                s = fmaf(w.y, f.y, s);
                s = fmaf(w.z, f.z, s);
                s = fmaf(w.w, f.w, s);
            }
        } else {
            #pragma unroll 8
            for (int k = 0; k < FD; ++k) s = fmaf(fs[k], ce_w1[k * 256 + t], s);
        }
        z1[t] = s > 0.f ? s : 0.f;
    }
    __syncthreads();

    if (t < 128) {
        float s = ce_b2[t];
        #pragma unroll 8
        for (int k = 0; k < 256; ++k) s = fmaf(z1[k], ce_w2[k * 128 + t], s);
        z2[t] = s > 0.f ? s : 0.f;
    }
    __syncthreads();

    if (t < 64) {
        float s = ce_b3[t];
        #pragma unroll 8
        for (int k = 0; k < 128; ++k) s = fmaf(z2[k], ce_w3[k * 64 + t], s);
        zc[t] = s;
    }
    __syncthreads();

    {
        float s = sf_b1[t];
        #pragma unroll 8
        for (int k = 0; k < 64; ++k) s = fmaf(zc[k], sf_w1[(2 + k) * 256 + t], s);
        zpart[b * HD + t] = s;
    }
}

// ---------------------------------------------------------------------------
// fused field MLP, fp8 MX K=128 (unit scales), weight-stationary, 4-deep
// pipeline, 1 barrier/2 tiles, padded-linear LDS, compile-time buffer
// indices (r21) + OPERAND PREFETCH: each GEMM issues all 4 ld32 (8
// ds_read_b128) BEFORE its 16-MFMA cluster, so later reads' LDS latency
// hides under earlier MFMAs (fine-grained lgkmcnt). acc lifetimes remain
// disjoint; peak live regs ~220 (tripwire: FETCH spike = spill).
//   grid=256 (1 block/CU), 512 thr (8 waves, 2/SIMD).
//   Sub-phase t: GEMM1(t)+epi1 ; GEMM2(t-2)+epi2 ; build h1(t+2) ; store(t-4)
// ---------------------------------------------------------------------------
__global__ __launch_bounds__(512, 2) void field_kernel(
    const float* __restrict__ coords,   // [4096,2]
    const float* __restrict__ sf_w1,    // [66,256] rows 0,1 used
    const float* __restrict__ zpart,    // [256,256]
    const unsigned char* __restrict__ w2t8, // [256 n][256 k] fp8
    const float* __restrict__ sf_b2,    // [256]
    const unsigned char* __restrict__ w3t8, // [128 n][256 k] fp8
    const float* __restrict__ sf_b3,    // [128]
    const float* __restrict__ sf_w4,    // [128]
    const float* __restrict__ sf_b4,    // [1]
    float* __restrict__ out)            // [256,4096]
{
    __shared__ __attribute__((aligned(128))) unsigned char h1[4][64 * HSTR];  // 68 KB
    __shared__ __attribute__((aligned(128))) unsigned char h2[4][64 * HSTR];  // 68 KB
    __shared__ float partials[4][64][20];                                     // 20 KB

    const int b = blockIdx.x;
    const int tid = threadIdx.x;
    const int wid = tid >> 6;
    const int lane = tid & 63;
    const int l15 = lane & 15;
    const int l4 = lane >> 4;
    const int koff = l4 * 32;          // lane's 32B k-slice within a 128-k step

    // ---- resident weights (MX K=128 fragments: lane k = ks*128 + l4*32 + 0..31) ----
    const int cg1 = wid & 3;    // GEMM1 col group (64 cols)
    const int rg1 = wid >> 2;   // GEMM1 row group (32 rows)
    i32x8 b1f[2][4];
    #pragma unroll
    for (int ks = 0; ks < 2; ++ks)
        #pragma unroll
        for (int n = 0; n < 4; ++n)
            b1f[ks][n] = *reinterpret_cast<const i32x8*>(
                &w2t8[(cg1 * 64 + n * 16 + l15) * 256 + ks * 128 + koff]);

    const int cgrp = wid & 3, rhalf = wid >> 2;
    i32x8 w3f[2][2];
    #pragma unroll
    for (int ks = 0; ks < 2; ++ks)
        #pragma unroll
        for (int cb = 0; cb < 2; ++cb)
            w3f[ks][cb] = *reinterpret_cast<const i32x8*>(
                &w3t8[(cgrp * 32 + cb * 16 + l15) * 256 + ks * 128 + koff]);

    // ---- resident bias / w4 vectors ----
    f32x4 b2r[4];
    #pragma unroll
    for (int n = 0; n < 4; ++n)
        b2r[n] = *reinterpret_cast<const f32x4*>(&sf_b2[cg1 * 64 + n * 16 + l4 * 4]);
    f32x4 b3r[2], w4r[2];
    #pragma unroll
    for (int cb = 0; cb < 2; ++cb) {
        b3r[cb] = *reinterpret_cast<const f32x4*>(&sf_b3[cgrp * 32 + cb * 16 + l4 * 4]);
        w4r[cb] = *reinterpret_cast<const f32x4*>(&sf_w4[cgrp * 32 + cb * 16 + l4 * 4]);
    }
    const float b4v = sf_b4[0];

    // ---- h1-build constants (meshgrid: xx tile-const, yy thread-invariant) ----
    const int kc = tid & 31;           // 8B chunk within row (linear)
    const int rbase = tid >> 5;        // row base 0..15 (rows rbase+16*it)
    float zpf[8], waf[8], wbf[8];
    #pragma unroll
    for (int j = 0; j < 8; ++j) {
        zpf[j] = zpart[b * HD + kc * 8 + j];
        waf[j] = sf_w1[kc * 8 + j];
        wbf[j] = sf_w1[HD + kc * 8 + j];
    }
    float xvr[4];
    #pragma unroll
    for (int it = 0; it < 4; ++it)
        xvr[it] = coords[2 * (it * 16 + rbase) + 1];   // yy = x[row], tile-invariant

    // contiguous 32B LDS operand: 2 x 16B (2 ds_read_b128)
    auto ld32 = [&](const unsigned char* p) -> i32x8 {
        uint4 a = *reinterpret_cast<const uint4*>(p);
        uint4 c = *reinterpret_cast<const uint4*>(p + 16);
        i32x8 r;
        r[0] = a.x; r[1] = a.y; r[2] = a.z; r[3] = a.w;
        r[4] = c.x; r[5] = c.y; r[6] = c.z; r[7] = c.w;
        return r;
    };

    // build tile t into buffer bi (bi literal at call sites)
    auto build = [&](int t, int bi) {
        unsigned char* buf = h1[bi];
        float x0 = coords[t * 128];    // xx tile-constant
        float zc8[8];
        #pragma unroll
        for (int j = 0; j < 8; ++j) zc8[j] = fmaf(x0, waf[j], zpf[j]);
        #pragma unroll
        for (int it = 0; it < 4; ++it) {
            float xv = xvr[it];
            float s[8];
            #pragma unroll
            for (int j = 0; j < 8; ++j) {
                float v = fmaf(xv, wbf[j], zc8[j]);
                s[j] = v > 0.f ? v : 0.f;
            }
            uint2 pk;
            pk.x = pack4_fp8(s[0], s[1], s[2], s[3]);
            pk.y = pack4_fp8(s[4], s[5], s[6], s[7]);
            *reinterpret_cast<uint2*>(&buf[(it * 16 + rbase) * HSTR + kc * 8]) = pk;
        }
    };

    // subphase with LITERAL tm = t mod 4 (all buffer indices compile-time)
    auto subphase = [&](int t, int tm) {
        const int tg2 = t - 2;
        const bool g1 = (t < 64);
        const bool g2 = (tg2 >= 0) && (tg2 < 64);
        const unsigned char* h1c = h1[tm];
        const unsigned char* h2p = h2[(tm + 2) & 3];   // (t-2) mod 4

        // ======== GEMM1(t) + epilogue1 (acc1 lifetime confined here) ========
        if (g1) {
            const unsigned char* r0 = h1c + (rg1 * 32 + l15) * HSTR + koff;
            const unsigned char* r1 = r0 + 16 * HSTR;
            // prefetch ALL operands: 8 ds_read_b128 in flight before MFMAs
            i32x8 a00 = ld32(r0);
            i32x8 a10 = ld32(r1);
            i32x8 a01 = ld32(r0 + 128);
            i32x8 a11 = ld32(r1 + 128);

            f32x4 acc1[2][4];
            #pragma unroll
            for (int m = 0; m < 2; ++m)
                #pragma unroll
                for (int n = 0; n < 4; ++n) acc1[m][n] = b2r[n];   // bias C-init

            __builtin_amdgcn_s_setprio(1);
            #pragma unroll
            for (int n = 0; n < 4; ++n)
                acc1[0][n] = MFMA_MX(b1f[0][n], a00, acc1[0][n]);
            #pragma unroll
            for (int n = 0; n < 4; ++n)
                acc1[1][n] = MFMA_MX(b1f[0][n], a10, acc1[1][n]);
            #pragma unroll
            for (int n = 0; n < 4; ++n)
                acc1[0][n] = MFMA_MX(b1f[1][n], a01, acc1[0][n]);
            #pragma unroll
            for (int n = 0; n < 4; ++n)
                acc1[1][n] = MFMA_MX(b1f[1][n], a11, acc1[1][n]);
            __builtin_amdgcn_s_setprio(0);

            // epilogue1: h2 = relu(acc1) (bias pre-added) -> h2[tm]
            unsigned char* h2c = h2[tm];
            #pragma unroll
            for (int n = 0; n < 4; ++n) {
                #pragma unroll
                for (int m = 0; m < 2; ++m) {
                    int row = rg1 * 32 + m * 16 + l15;
                    int col = cg1 * 64 + n * 16 + l4 * 4;
                    float x0 = fmaxf(acc1[m][n][0], 0.f);
                    float x1 = fmaxf(acc1[m][n][1], 0.f);
                    float x2 = fmaxf(acc1[m][n][2], 0.f);
                    float x3 = fmaxf(acc1[m][n][3], 0.f);
                    *reinterpret_cast<unsigned int*>(&h2c[row * HSTR + col]) =
                        pack4_fp8(x0, x1, x2, x3);
                }
            }
        }

        // ======== GEMM2(t-2) + epilogue2 (acc2 lifetime confined here) ========
        if (g2) {
            const unsigned char* r0 = h2p + (rhalf * 32 + l15) * HSTR + koff;
            const unsigned char* r1 = r0 + 16 * HSTR;
            i32x8 h00 = ld32(r0);
            i32x8 h10 = ld32(r1);
            i32x8 h01 = ld32(r0 + 128);
            i32x8 h11 = ld32(r1 + 128);

            f32x4 acc2[2][2] = {};   // zero init; b3 added in epilogue
            __builtin_amdgcn_s_setprio(1);
            #pragma unroll
            for (int cb = 0; cb < 2; ++cb)
                acc2[0][cb] = MFMA_MX(w3f[0][cb], h00, acc2[0][cb]);
            #pragma unroll
            for (int cb = 0; cb < 2; ++cb)
                acc2[1][cb] = MFMA_MX(w3f[0][cb], h10, acc2[1][cb]);
            #pragma unroll
            for (int cb = 0; cb < 2; ++cb)
                acc2[0][cb] = MFMA_MX(w3f[1][cb], h01, acc2[0][cb]);
            #pragma unroll
            for (int cb = 0; cb < 2; ++cb)
                acc2[1][cb] = MFMA_MX(w3f[1][cb], h11, acc2[1][cb]);
            __builtin_amdgcn_s_setprio(0);

            // epilogue2: relu (resident b3) + w4 dot -> partials[(tm+2)&3]
            #pragma unroll
            for (int rb = 0; rb < 2; ++rb) {
                float pp = 0.f;
                #pragma unroll
                for (int cb = 0; cb < 2; ++cb)
                    #pragma unroll
                    for (int i = 0; i < 4; ++i) {
                        float v = fmaxf(acc2[rb][cb][i] + b3r[cb][i], 0.f);
                        pp = fmaf(v, w4r[cb][i], pp);
                    }
                partials[(tm + 2) & 3][rhalf * 32 + rb * 16 + l15][cgrp * 4 + l4] = pp;
            }
        }

        // build h1 for tile t+2 into h1[(tm+2)&3] (read after the barrier)
        if (t + 2 < 64) build(t + 2, (tm + 2) & 3);

        // final store for tile t-4 (partials[tm], written one pair ago)
        const int tf = t - 4;
        if (tf >= 0 && tid < 64) {
            const f32x4* pr = reinterpret_cast<const f32x4*>(&partials[tm][tid][0]);
            f32x4 ss = pr[0] + pr[1] + pr[2] + pr[3];
            float s = ss[0] + ss[1] + ss[2] + ss[3] + b4v;
            out[b * GG + tf * 64 + tid] = 1.f / (1.f + __expf(-s));
        }
    };

    // prologue: tiles 0 and 1
    build(0, 0);
    build(1, 1);
    __syncthreads();

    #pragma unroll 1
    for (int t0 = 0; t0 < 68; t0 += 4) {
        subphase(t0,     0);
        subphase(t0 + 1, 1);
        __syncthreads();
        subphase(t0 + 2, 2);
        subphase(t0 + 3, 3);
        __syncthreads();
    }
}

// ---------------------------------------------------------------------------
extern "C" void kernel_launch(void* const* d_in, const int* in_sizes, int n_in,
                              void* d_out, int out_size, void* d_ws, size_t ws_size,
                              hipStream_t stream)
{
    const float* features = (const float*)d_in[0];
    const float* coords   = (const float*)d_in[1];
    const float* ce_w1 = (const float*)d_in[2];
    const float* ce_b1 = (const float*)d_in[3];
    const float* ce_w2 = (const float*)d_in[4];
    const float* ce_b2 = (const float*)d_in[5];
    const float* ce_w3 = (const float*)d_in[6];
    const float* ce_b3 = (const float*)d_in[7];
    const float* sf_w1 = (const float*)d_in[8];
    const float* sf_b1 = (const float*)d_in[9];
    const float* sf_w2 = (const float*)d_in[10];
    const float* sf_b2 = (const float*)d_in[11];
    const float* sf_w3 = (const float*)d_in[12];
    const float* sf_b3 = (const float*)d_in[13];
    const float* sf_w4 = (const float*)d_in[14];
    const float* sf_b4 = (const float*)d_in[15];
    float* out = (float*)d_out;

    char* ws = (char*)d_ws;
    float*        zpart = (float*)ws;                             // 256 KB
    unsigned int* w2t8  = (unsigned int*)(ws + 262144);           //  64 KB
    unsigned int* w3t8  = (unsigned int*)(ws + 262144 + 65536);   //  32 KB
    float*        w1t   = (float*)(ws + 262144 + 65536 + 32768);  //   1 MB (optional)
    const size_t need_w1t = (size_t)(262144 + 65536 + 32768) + (size_t)FD * HD * 4;
    float* w1t_ptr = (ws_size >= need_w1t) ? w1t : nullptr;

    hipLaunchKernelGGL(prep_kernel, dim3(1024), dim3(256), 0, stream,
                       ce_w1, sf_w2, sf_w3, w1t_ptr, w2t8, w3t8);
    hipLaunchKernelGGL(ce_kernel, dim3(256), dim3(256), 0, stream,
                       features, ce_w1, w1t_ptr, ce_b1, ce_w2, ce_b2, ce_w3, ce_b3,
                       sf_w1, sf_b1, zpart);
    hipLaunchKernelGGL(field_kernel, dim3(256), dim3(512), 0, stream,
                       coords, sf_w1, zpart,
                       (const unsigned char*)w2t8, sf_b2,
                       (const unsigned char*)w3t8, sf_b3, sf_w4, sf_b4, out);
}

// Round 23
// 127.622 us; speedup vs baseline: 4.6627x; 1.2260x over previous
//
#include <hip/hip_runtime.h>
#include <hip/hip_bf16.h>

typedef __bf16 bf16_t;
typedef __attribute__((ext_vector_type(4))) float f32x4;
typedef __attribute__((ext_vector_type(8))) int i32x8;

#define FD 1024
#define HD 256
#define GG 4096
#define HSTR 272   // padded LDS row stride (bytes)

// pack 4 f32 -> 4 OCP e4m3 bytes (v_cvt_pk_fp8_f32, gfx950 = OCP)
__device__ inline unsigned int pack4_fp8(float a, float b, float c, float d) {
    int v = __builtin_amdgcn_cvt_pk_fp8_f32(a, b, 0, false);
    v = __builtin_amdgcn_cvt_pk_fp8_f32(c, d, v, true);
    return (unsigned int)v;
}

// MX-scaled MFMA, fp8(e4m3) A/B, K=128, UNIT scales (exact; verified r14/r15)
#define MFMA_MX(A, B, C) \
    __builtin_amdgcn_mfma_scale_f32_16x16x128_f8f6f4((A), (B), (C), 0, 0, 0, 127, 0, 127)

// ---------------------------------------------------------------------------
// merged prep + context encoder: 256 blocks x 512 thr.
//   - block b computes CE for batch b (split-K at every layer, all threads busy)
//   - each block also converts its 96-item slice of w2t8/w3t8 (fp8 N-major)
//   Replaces two kernels (prep, ce) + the 1 MB w1t transpose (direct
//   coalesced ce_w1 column reads are faster than uncoalesced w1t rows).
// ---------------------------------------------------------------------------
__global__ __launch_bounds__(512) void prep_ce_kernel(
    const float* __restrict__ features,   // [256,1024]
    const float* __restrict__ ce_w1,      // [1024,256]
    const float* __restrict__ ce_b1,
    const float* __restrict__ ce_w2, const float* __restrict__ ce_b2,
    const float* __restrict__ ce_w3, const float* __restrict__ ce_b3,
    const float* __restrict__ sf_w1,      // [66,256]
    const float* __restrict__ sf_b1,
    const float* __restrict__ sf_w2,      // [256,256]
    const float* __restrict__ sf_w3,      // [256,128]
    float* __restrict__ zpart,            // [256,256]
    unsigned int* __restrict__ w2t8,      // [256 n][256 k] fp8, as u32[16384]
    unsigned int* __restrict__ w3t8)      // [128 n][256 k] fp8, as u32[8192]
{
    const int b = blockIdx.x;
    const int t = threadIdx.x;

    // ---- cooperative weight conversion: 24576 u32 = 256 blocks x 96 ----
    if (t < 96) {
        int id = b * 96 + t;
        if (id < 16384) {
            int n = id >> 6, k4 = (id & 63) << 2;
            w2t8[id] = pack4_fp8(sf_w2[(k4 + 0) * 256 + n], sf_w2[(k4 + 1) * 256 + n],
                                 sf_w2[(k4 + 2) * 256 + n], sf_w2[(k4 + 3) * 256 + n]);
        } else {
            int id3 = id - 16384;
            int n = id3 >> 6, k4 = (id3 & 63) << 2;
            w3t8[id3] = pack4_fp8(sf_w3[(k4 + 0) * 128 + n], sf_w3[(k4 + 1) * 128 + n],
                                 sf_w3[(k4 + 2) * 128 + n], sf_w3[(k4 + 3) * 128 + n]);
        }
    }

    // ---- CE for batch b ----
    __shared__ float fs[FD];
    __shared__ float pp[512];
    __shared__ float z1[HD];
    __shared__ float z2[HD / 2];
    __shared__ float zc[64];

    fs[t] = features[b * FD + t];
    fs[t + 512] = features[b * FD + t + 512];
    __syncthreads();

    // layer 1: 1024 -> 256, split-K x2 (o = t&255, half = t>>8)
    {
        const int o = t & 255, h = t >> 8;
        float s = 0.f;
        const float* w = ce_w1 + (h * 512) * 256 + o;
        const float* f = fs + h * 512;
        #pragma unroll 8
        for (int k = 0; k < 512; ++k) s = fmaf(f[k], w[k * 256], s);
        pp[t] = s;
    }
    __syncthreads();
    if (t < 256) {
        float s = pp[t] + pp[t + 256] + ce_b1[t];
        z1[t] = s > 0.f ? s : 0.f;
    }
    __syncthreads();

    // layer 2: 256 -> 128, split-K x4 (o = t&127, q = t>>7)
    {
        const int o = t & 127, q = t >> 7;
        float s = 0.f;
        const float* w = ce_w2 + (q * 64) * 128 + o;
        const float* zz = z1 + q * 64;
        #pragma unroll 8
        for (int k = 0; k < 64; ++k) s = fmaf(zz[k], w[k * 128], s);
        pp[t] = s;
    }
    __syncthreads();
    if (t < 128) {
        float s = pp[t] + pp[t + 128] + pp[t + 256] + pp[t + 384] + ce_b2[t];
        z2[t] = s > 0.f ? s : 0.f;
    }
    __syncthreads();

    // layer 3: 128 -> 64 (no relu), split-K x8 (o = t&63, q = t>>6)
    {
        const int o = t & 63, q = t >> 6;
        float s = 0.f;
        const float* w = ce_w3 + (q * 16) * 64 + o;
        const float* zz = z2 + q * 16;
        #pragma unroll
        for (int k = 0; k < 16; ++k) s = fmaf(zz[k], w[k * 64], s);
        pp[t] = s;
    }
    __syncthreads();
    if (t < 64) {
        float s = ce_b3[t];
        #pragma unroll
        for (int q = 0; q < 8; ++q) s += pp[t + q * 64];
        zc[t] = s;
    }
    __syncthreads();

    // zpart = zc @ sf_w1[2:] + sf_b1, split-K x2 (o = t&255, h = t>>8)
    {
        const int o = t & 255, h = t >> 8;
        float s = 0.f;
        #pragma unroll 8
        for (int k = 0; k < 32; ++k)
            s = fmaf(zc[h * 32 + k], sf_w1[(2 + h * 32 + k) * 256 + o], s);
        pp[t] = s;
    }
    __syncthreads();
    if (t < 256) zpart[b * HD + t] = pp[t] + pp[t + 256] + sf_b1[t];
}

// ---------------------------------------------------------------------------
// fused field MLP, fp8 MX K=128 (unit scales), weight-stationary, 4-deep
// pipeline, 1 barrier/2 tiles, padded-linear LDS, compile-time buffer
// indices + operand prefetch (r22 structure -- best measured: ~135 us).
//   grid=256 (1 block/CU), 512 thr (8 waves, 2/SIMD).
//   Sub-phase t: GEMM1(t)+epi1 ; GEMM2(t-2)+epi2 ; build h1(t+2) ; store(t-4)
// ---------------------------------------------------------------------------
__global__ __launch_bounds__(512, 2) void field_kernel(
    const float* __restrict__ coords,   // [4096,2]
    const float* __restrict__ sf_w1,    // [66,256] rows 0,1 used
    const float* __restrict__ zpart,    // [256,256]
    const unsigned char* __restrict__ w2t8, // [256 n][256 k] fp8
    const float* __restrict__ sf_b2,    // [256]
    const unsigned char* __restrict__ w3t8, // [128 n][256 k] fp8
    const float* __restrict__ sf_b3,    // [128]
    const float* __restrict__ sf_w4,    // [128]
    const float* __restrict__ sf_b4,    // [1]
    float* __restrict__ out)            // [256,4096]
{
    __shared__ __attribute__((aligned(128))) unsigned char h1[4][64 * HSTR];  // 68 KB
    __shared__ __attribute__((aligned(128))) unsigned char h2[4][64 * HSTR];  // 68 KB
    __shared__ float partials[4][64][20];                                     // 20 KB

    const int b = blockIdx.x;
    const int tid = threadIdx.x;
    const int wid = tid >> 6;
    const int lane = tid & 63;
    const int l15 = lane & 15;
    const int l4 = lane >> 4;
    const int koff = l4 * 32;          // lane's 32B k-slice within a 128-k step

    // ---- resident weights (MX K=128 fragments: lane k = ks*128 + l4*32 + 0..31) ----
    const int cg1 = wid & 3;    // GEMM1 col group (64 cols)
    const int rg1 = wid >> 2;   // GEMM1 row group (32 rows)
    i32x8 b1f[2][4];
    #pragma unroll
    for (int ks = 0; ks < 2; ++ks)
        #pragma unroll
        for (int n = 0; n < 4; ++n)
            b1f[ks][n] = *reinterpret_cast<const i32x8*>(
                &w2t8[(cg1 * 64 + n * 16 + l15) * 256 + ks * 128 + koff]);

    const int cgrp = wid & 3, rhalf = wid >> 2;
    i32x8 w3f[2][2];
    #pragma unroll
    for (int ks = 0; ks < 2; ++ks)
        #pragma unroll
        for (int cb = 0; cb < 2; ++cb)
            w3f[ks][cb] = *reinterpret_cast<const i32x8*>(
                &w3t8[(cgrp * 32 + cb * 16 + l15) * 256 + ks * 128 + koff]);

    // ---- resident bias / w4 vectors ----
    f32x4 b2r[4];
    #pragma unroll
    for (int n = 0; n < 4; ++n)
        b2r[n] = *reinterpret_cast<const f32x4*>(&sf_b2[cg1 * 64 + n * 16 + l4 * 4]);
    f32x4 b3r[2], w4r[2];
    #pragma unroll
    for (int cb = 0; cb < 2; ++cb) {
        b3r[cb] = *reinterpret_cast<const f32x4*>(&sf_b3[cgrp * 32 + cb * 16 + l4 * 4]);
        w4r[cb] = *reinterpret_cast<const f32x4*>(&sf_w4[cgrp * 32 + cb * 16 + l4 * 4]);
    }
    const float b4v = sf_b4[0];

    // ---- h1-build constants (meshgrid: xx tile-const, yy thread-invariant) ----
    const int kc = tid & 31;           // 8B chunk within row (linear)
    const int rbase = tid >> 5;        // row base 0..15 (rows rbase+16*it)
    float zpf[8], waf[8], wbf[8];
    #pragma unroll
    for (int j = 0; j < 8; ++j) {
        zpf[j] = zpart[b * HD + kc * 8 + j];
        waf[j] = sf_w1[kc * 8 + j];
        wbf[j] = sf_w1[HD + kc * 8 + j];
    }
    float xvr[4];
    #pragma unroll
    for (int it = 0; it < 4; ++it)
        xvr[it] = coords[2 * (it * 16 + rbase) + 1];   // yy = x[row], tile-invariant

    // contiguous 32B LDS operand: 2 x 16B (2 ds_read_b128)
    auto ld32 = [&](const unsigned char* p) -> i32x8 {
        uint4 a = *reinterpret_cast<const uint4*>(p);
        uint4 c = *reinterpret_cast<const uint4*>(p + 16);
        i32x8 r;
        r[0] = a.x; r[1] = a.y; r[2] = a.z; r[3] = a.w;
        r[4] = c.x; r[5] = c.y; r[6] = c.z; r[7] = c.w;
        return r;
    };

    // build tile t into buffer bi (bi literal at call sites)
    auto build = [&](int t, int bi) {
        unsigned char* buf = h1[bi];
        float x0 = coords[t * 128];    // xx tile-constant
        float zc8[8];
        #pragma unroll
        for (int j = 0; j < 8; ++j) zc8[j] = fmaf(x0, waf[j], zpf[j]);
        #pragma unroll
        for (int it = 0; it < 4; ++it) {
            float xv = xvr[it];
            float s[8];
            #pragma unroll
            for (int j = 0; j < 8; ++j) {
                float v = fmaf(xv, wbf[j], zc8[j]);
                s[j] = v > 0.f ? v : 0.f;
            }
            uint2 pk;
            pk.x = pack4_fp8(s[0], s[1], s[2], s[3]);
            pk.y = pack4_fp8(s[4], s[5], s[6], s[7]);
            *reinterpret_cast<uint2*>(&buf[(it * 16 + rbase) * HSTR + kc * 8]) = pk;
        }
    };

    // subphase with LITERAL tm = t mod 4 (all buffer indices compile-time)
    auto subphase = [&](int t, int tm) {
        const int tg2 = t - 2;
        const bool g1 = (t < 64);
        const bool g2 = (tg2 >= 0) && (tg2 < 64);
        const unsigned char* h1c = h1[tm];
        const unsigned char* h2p = h2[(tm + 2) & 3];   // (t-2) mod 4

        // ======== GEMM1(t) + epilogue1 (acc1 lifetime confined here) ========
        if (g1) {
            const unsigned char* r0 = h1c + (rg1 * 32 + l15) * HSTR + koff;
            const unsigned char* r1 = r0 + 16 * HSTR;
            // prefetch ALL operands: 8 ds_read_b128 in flight before MFMAs
            i32x8 a00 = ld32(r0);
            i32x8 a10 = ld32(r1);
            i32x8 a01 = ld32(r0 + 128);
            i32x8 a11 = ld32(r1 + 128);

            f32x4 acc1[2][4];
            #pragma unroll
            for (int m = 0; m < 2; ++m)
                #pragma unroll
                for (int n = 0; n < 4; ++n) acc1[m][n] = b2r[n];   // bias C-init

            __builtin_amdgcn_s_setprio(1);
            #pragma unroll
            for (int n = 0; n < 4; ++n)
                acc1[0][n] = MFMA_MX(b1f[0][n], a00, acc1[0][n]);
            #pragma unroll
            for (int n = 0; n < 4; ++n)
                acc1[1][n] = MFMA_MX(b1f[0][n], a10, acc1[1][n]);
            #pragma unroll
            for (int n = 0; n < 4; ++n)
                acc1[0][n] = MFMA_MX(b1f[1][n], a01, acc1[0][n]);
            #pragma unroll
            for (int n = 0; n < 4; ++n)
                acc1[1][n] = MFMA_MX(b1f[1][n], a11, acc1[1][n]);
            __builtin_amdgcn_s_setprio(0);

            // epilogue1: h2 = relu(acc1) (bias pre-added) -> h2[tm]
            unsigned char* h2c = h2[tm];
            #pragma unroll
            for (int n = 0; n < 4; ++n) {
                #pragma unroll
                for (int m = 0; m < 2; ++m) {
                    int row = rg1 * 32 + m * 16 + l15;
                    int col = cg1 * 64 + n * 16 + l4 * 4;
                    float x0 = fmaxf(acc1[m][n][0], 0.f);
                    float x1 = fmaxf(acc1[m][n][1], 0.f);
                    float x2 = fmaxf(acc1[m][n][2], 0.f);
                    float x3 = fmaxf(acc1[m][n][3], 0.f);
                    *reinterpret_cast<unsigned int*>(&h2c[row * HSTR + col]) =
                        pack4_fp8(x0, x1, x2, x3);
                }
            }
        }

        // ======== GEMM2(t-2) + epilogue2 (acc2 lifetime confined here) ========
        if (g2) {
            const unsigned char* r0 = h2p + (rhalf * 32 + l15) * HSTR + koff;
            const unsigned char* r1 = r0 + 16 * HSTR;
            i32x8 h00 = ld32(r0);
            i32x8 h10 = ld32(r1);
            i32x8 h01 = ld32(r0 + 128);
            i32x8 h11 = ld32(r1 + 128);

            f32x4 acc2[2][2] = {};   // zero init; b3 added in epilogue
            __builtin_amdgcn_s_setprio(1);
            #pragma unroll
            for (int cb = 0; cb < 2; ++cb)
                acc2[0][cb] = MFMA_MX(w3f[0][cb], h00, acc2[0][cb]);
            #pragma unroll
            for (int cb = 0; cb < 2; ++cb)
                acc2[1][cb] = MFMA_MX(w3f[0][cb], h10, acc2[1][cb]);
            #pragma unroll
            for (int cb = 0; cb < 2; ++cb)
                acc2[0][cb] = MFMA_MX(w3f[1][cb], h01, acc2[0][cb]);
            #pragma unroll
            for (int cb = 0; cb < 2; ++cb)
                acc2[1][cb] = MFMA_MX(w3f[1][cb], h11, acc2[1][cb]);
            __builtin_amdgcn_s_setprio(0);

            // epilogue2: relu (resident b3) + w4 dot -> partials[(tm+2)&3]
            #pragma unroll
            for (int rb = 0; rb < 2; ++rb) {
                float pp = 0.f;
                #pragma unroll
                for (int cb = 0; cb < 2; ++cb)
                    #pragma unroll
                    for (int i = 0; i < 4; ++i) {
                        float v = fmaxf(acc2[rb][cb][i] + b3r[cb][i], 0.f);
                        pp = fmaf(v, w4r[cb][i], pp);
                    }
                partials[(tm + 2) & 3][rhalf * 32 + rb * 16 + l15][cgrp * 4 + l4] = pp;
            }
        }

        // build h1 for tile t+2 into h1[(tm+2)&3] (read after the barrier)
        if (t + 2 < 64) build(t + 2, (tm + 2) & 3);

        // final store for tile t-4 (partials[tm], written one pair ago)
        const int tf = t - 4;
        if (tf >= 0 && tid < 64) {
            const f32x4* pr = reinterpret_cast<const f32x4*>(&partials[tm][tid][0]);
            f32x4 ss = pr[0] + pr[1] + pr[2] + pr[3];
            float s = ss[0] + ss[1] + ss[2] + ss[3] + b4v;
            out[b * GG + tf * 64 + tid] = 1.f / (1.f + __expf(-s));
        }
    };

    // prologue: tiles 0 and 1
    build(0, 0);
    build(1, 1);
    __syncthreads();

    #pragma unroll 1
    for (int t0 = 0; t0 < 68; t0 += 4) {
        subphase(t0,     0);
        subphase(t0 + 1, 1);
        __syncthreads();
        subphase(t0 + 2, 2);
        subphase(t0 + 3, 3);
        __syncthreads();
    }
}

// ---------------------------------------------------------------------------
extern "C" void kernel_launch(void* const* d_in, const int* in_sizes, int n_in,
                              void* d_out, int out_size, void* d_ws, size_t ws_size,
                              hipStream_t stream)
{
    const float* features = (const float*)d_in[0];
    const float* coords   = (const float*)d_in[1];
    const float* ce_w1 = (const float*)d_in[2];
    const float* ce_b1 = (const float*)d_in[3];
    const float* ce_w2 = (const float*)d_in[4];
    const float* ce_b2 = (const float*)d_in[5];
    const float* ce_w3 = (const float*)d_in[6];
    const float* ce_b3 = (const float*)d_in[7];
    const float* sf_w1 = (const float*)d_in[8];
    const float* sf_b1 = (const float*)d_in[9];
    const float* sf_w2 = (const float*)d_in[10];
    const float* sf_b2 = (const float*)d_in[11];
    const float* sf_w3 = (const float*)d_in[12];
    const float* sf_b3 = (const float*)d_in[13];
    const float* sf_w4 = (const float*)d_in[14];
    const float* sf_b4 = (const float*)d_in[15];
    float* out = (float*)d_out;

    char* ws = (char*)d_ws;
    float*        zpart = (float*)ws;                             // 256 KB
    unsigned int* w2t8  = (unsigned int*)(ws + 262144);           //  64 KB
    unsigned int* w3t8  = (unsigned int*)(ws + 262144 + 65536);   //  32 KB

    hipLaunchKernelGGL(prep_ce_kernel, dim3(256), dim3(512), 0, stream,
                       features, ce_w1, ce_b1, ce_w2, ce_b2, ce_w3, ce_b3,
                       sf_w1, sf_b1, sf_w2, sf_w3, zpart, w2t8, w3t8);
    hipLaunchKernelGGL(field_kernel, dim3(256), dim3(512), 0, stream,
                       coords, sf_w1, zpart,
                       (const unsigned char*)w2t8, sf_b2,
                       (const unsigned char*)w3t8, sf_b3, sf_w4, sf_b4, out);
}